// Round 6
// baseline (981.446 us; speedup 1.0000x reference)
//
#include <hip/hip_runtime.h>
#include <math.h>

// Problem constants (fixed by the reference)
#define B_SZ 2
#define L_SEQ 4096
#define D_MODEL 1024
#define D_INNER 2048
#define D_STATE 64
#define DT_RANK 128
#define BL (B_SZ * L_SEQ)          // 8192 tokens

#define AS1 __attribute__((address_space(1)))
#define AS3 __attribute__((address_space(3)))

typedef __attribute__((ext_vector_type(8))) short bf16x8_t;  // 8 bf16 = 4 VGPRs
typedef __attribute__((ext_vector_type(4))) float f32x4_t;
typedef __attribute__((ext_vector_type(2))) unsigned int u32x2_t;

__device__ __forceinline__ unsigned short f2bf(float f) {
    unsigned int u = __float_as_uint(f);
    u = (u + 0x7FFFu + ((u >> 16) & 1u)) >> 16;   // RNE
    return (unsigned short)u;
}
__device__ __forceinline__ float bf2f(unsigned short h) {
    return __uint_as_float(((unsigned int)h) << 16);
}

// ---------------------------------------------------------------------------
// fp32 -> bf16 bulk convert (n4 = count of float4 groups)
// ---------------------------------------------------------------------------
__global__ __launch_bounds__(256) void cvt_f32_bf16(
    const float* __restrict__ in, unsigned short* __restrict__ out, int n4)
{
    int i = blockIdx.x * 256 + threadIdx.x;
    if (i >= n4) return;
    float4 v = ((const float4*)in)[i];
    ushort4 o;
    o.x = f2bf(v.x); o.y = f2bf(v.y); o.z = f2bf(v.z); o.w = f2bf(v.w);
    ((ushort4*)out)[i] = o;
}

// xdbl[:, :128] (fp32, row stride 256) -> packed bf16 [8192][128]
__global__ __launch_bounds__(256) void cvt_dtpart(
    const float* __restrict__ xdbl, unsigned short* __restrict__ out)
{
    int i = blockIdx.x * 256 + threadIdx.x;   // 0 .. 8192*32-1
    int m = i >> 5, c = i & 31;
    float4 v = *(const float4*)(xdbl + (size_t)m * 256 + c * 4);
    ushort4 o;
    o.x = f2bf(v.x); o.y = f2bf(v.y); o.z = f2bf(v.z); o.w = f2bf(v.w);
    ((ushort4*)(out))[(size_t)m * 32 + c] = o;
}

// ---------------------------------------------------------------------------
// bf16 MFMA GEMM: C[m][n] = act( sum_k A[m][k]*B[n][k] [+ bias[m]] )
// A: M x K bf16 row-major (lda), B: N x K bf16 row-major (ldb), C fp32 (ldc).
// act: 0 none, 1 softplus with bias indexed by ROW m, 2 silu.
// Tile 128x128, BK=32, 256 threads = 4 waves (2x2 of 64x64 per wave).
// ---------------------------------------------------------------------------
__global__ __launch_bounds__(256) void gemm_bf16(
    const unsigned short* __restrict__ A, int lda,
    const unsigned short* __restrict__ B, int ldb,
    float* __restrict__ C, int ldc, int K,
    const float* __restrict__ bias, int act)
{
    __shared__ unsigned short As[128 * 32];   // [row][k] linear, no pad
    __shared__ unsigned short Bs[128 * 32];

    const int tid = threadIdx.x;
    const int w = tid >> 6, lane = tid & 63;
    const int bm = blockIdx.y * 128, bn = blockIdx.x * 128;
    const int wm = (w & 1) * 64, wn = (w >> 1) * 64;

    f32x4_t acc[4][4];
#pragma unroll
    for (int i = 0; i < 4; ++i)
#pragma unroll
        for (int j = 0; j < 4; ++j) acc[i][j] = (f32x4_t){0.f, 0.f, 0.f, 0.f};

    const int srow = lane >> 2;
    const int scol = (lane & 3) * 8;
    const unsigned short* Ag0 = A + (size_t)(bm + w * 16 + srow) * lda + scol;
    const unsigned short* Ag1 = A + (size_t)(bm + 64 + w * 16 + srow) * lda + scol;
    const unsigned short* Bg0 = B + (size_t)(bn + w * 16 + srow) * ldb + scol;
    const unsigned short* Bg1 = B + (size_t)(bn + 64 + w * 16 + srow) * ldb + scol;
    unsigned short* la0 = &As[(w * 16) * 32];
    unsigned short* la1 = &As[(64 + w * 16) * 32];
    unsigned short* lb0 = &Bs[(w * 16) * 32];
    unsigned short* lb1 = &Bs[(64 + w * 16) * 32];

    const int fr = lane & 15;
    const int fk = (lane >> 4) * 8;

    for (int k0 = 0; k0 < K; k0 += 32) {
        __syncthreads();
        __builtin_amdgcn_global_load_lds((const AS1 void*)(Ag0 + k0), (AS3 void*)la0, 16, 0, 0);
        __builtin_amdgcn_global_load_lds((const AS1 void*)(Ag1 + k0), (AS3 void*)la1, 16, 0, 0);
        __builtin_amdgcn_global_load_lds((const AS1 void*)(Bg0 + k0), (AS3 void*)lb0, 16, 0, 0);
        __builtin_amdgcn_global_load_lds((const AS1 void*)(Bg1 + k0), (AS3 void*)lb1, 16, 0, 0);
        __syncthreads();

        bf16x8_t af[4], bfr[4];
#pragma unroll
        for (int i = 0; i < 4; ++i)
            af[i] = *(const bf16x8_t*)&As[(wm + i * 16 + fr) * 32 + fk];
#pragma unroll
        for (int j = 0; j < 4; ++j)
            bfr[j] = *(const bf16x8_t*)&Bs[(wn + j * 16 + fr) * 32 + fk];
#pragma unroll
        for (int i = 0; i < 4; ++i)
#pragma unroll
            for (int j = 0; j < 4; ++j)
                acc[i][j] = __builtin_amdgcn_mfma_f32_16x16x32_bf16(
                    af[i], bfr[j], acc[i][j], 0, 0, 0);
    }

    const int erow = (lane >> 4) * 4;
    const int ecol = lane & 15;
#pragma unroll
    for (int i = 0; i < 4; ++i) {
        int gr0 = bm + wm + i * 16 + erow;
#pragma unroll
        for (int j = 0; j < 4; ++j) {
            int gc = bn + wn + j * 16 + ecol;
#pragma unroll
            for (int r = 0; r < 4; ++r) {
                float v = acc[i][j][r];
                if (act == 1) {
                    float t = v + bias[gr0 + r];
                    v = (t > 20.f) ? t : log1pf(__expf(t));
                } else if (act == 2) {
                    v = v / (1.f + __expf(-v));
                }
                C[(size_t)(gr0 + r) * ldc + gc] = v;
            }
        }
    }
}

// ---------------------------------------------------------------------------
// causal depthwise conv (k=4) + bias + silu on [d][m] layout, bf16 output.
// ---------------------------------------------------------------------------
__global__ __launch_bounds__(256) void conv_silu_kernel(
    const float* __restrict__ xT,     // [2048][8192] fp32
    const float* __restrict__ w,      // [2048][4]
    const float* __restrict__ bias,   // [2048]
    unsigned short* __restrict__ xcT16) // [2048][8192] bf16
{
    int gid = blockIdx.x * blockDim.x + threadIdx.x;  // 0 .. 2048*2048-1
    int d = gid >> 11;
    int c4 = gid & 2047;
    int m0 = c4 * 4;
    int l0 = m0 & (L_SEQ - 1);

    const float* row = xT + (size_t)d * BL;
    float4 v = *(const float4*)(row + m0);
    float4 p;
    if (l0 == 0) { p.x = p.y = p.z = p.w = 0.f; }
    else         { p = *(const float4*)(row + m0 - 4); }

    float4 wv = ((const float4*)w)[d];
    float bb = bias[d];
    float e[4];
    e[0] = bb + wv.x * p.y + wv.y * p.z + wv.z * p.w + wv.w * v.x;
    e[1] = bb + wv.x * p.z + wv.y * p.w + wv.z * v.x + wv.w * v.y;
    e[2] = bb + wv.x * p.w + wv.y * v.x + wv.z * v.y + wv.w * v.z;
    e[3] = bb + wv.x * v.x + wv.y * v.y + wv.z * v.z + wv.w * v.w;
    ushort4 o;
    o.x = f2bf(e[0] / (1.f + __expf(-e[0])));
    o.y = f2bf(e[1] / (1.f + __expf(-e[1])));
    o.z = f2bf(e[2] / (1.f + __expf(-e[2])));
    o.w = f2bf(e[3] / (1.f + __expf(-e[3])));
    ((ushort4*)(xcT16 + (size_t)d * BL))[c4] = o;
}

// ---------------------------------------------------------------------------
// 32x32 tiled transposes (coalesced both sides)
// ---------------------------------------------------------------------------
__global__ __launch_bounds__(256) void transpose_f32_bf16(
    const float* __restrict__ in, int ldin,
    unsigned short* __restrict__ out, int ldout)
{
    __shared__ float tl[32][33];
    int r0 = blockIdx.y * 32, c0 = blockIdx.x * 32;
    int tx = threadIdx.x & 31, ty = threadIdx.x >> 5;
#pragma unroll
    for (int k = 0; k < 4; ++k)
        tl[ty + 8 * k][tx] = in[(size_t)(r0 + ty + 8 * k) * ldin + c0 + tx];
    __syncthreads();
#pragma unroll
    for (int k = 0; k < 4; ++k)
        out[(size_t)(c0 + ty + 8 * k) * ldout + r0 + tx] = f2bf(tl[tx][ty + 8 * k]);
}

__global__ __launch_bounds__(256) void transpose_bf16(
    const unsigned short* __restrict__ in, int ldin,
    unsigned short* __restrict__ out, int ldout)
{
    __shared__ unsigned short tl[32][33];
    int r0 = blockIdx.y * 32, c0 = blockIdx.x * 32;
    int tx = threadIdx.x & 31, ty = threadIdx.x >> 5;
#pragma unroll
    for (int k = 0; k < 4; ++k)
        tl[ty + 8 * k][tx] = in[(size_t)(r0 + ty + 8 * k) * ldin + c0 + tx];
    __syncthreads();
#pragma unroll
    for (int k = 0; k < 4; ++k)
        out[(size_t)(c0 + ty + 8 * k) * ldout + r0 + tx] = tl[tx][ty + 8 * k];
}

// ---------------------------------------------------------------------------
// Single-pass selective scan: ONE WAVE per (b,d) sequence, 16 waves/block,
// ONE block per CU (grid=256, LDS 82KB forces 1 block/CU -> balanced).
//   R4 post-mortem: saddr/dtx/s_y bundle regressed (471->500); reverted to
//   the R3 body. R5 levers:
//   (1) CU-wide lockstep: all 16 waves of a CU scan the same t-range; a raw
//       s_barrier (no waitcnt drain -- LDS slices are wave-private, barrier
//       is only a rate-limiter) every 32 steps bounds drift to a 16KB B/C
//       window < L1, so the shared B/C stream (same batch per XCD via
//       bi&1 == xcd&1) is served from L1/coalesced-MSHR instead of L2.
//       B/C L2 traffic was ~8.6GB (~250us) -- the unexplained gap in the
//       R3 cost model.
//   (2) Fold stages xor32/xor16 -> v_permlane{32,16}_swap_b32 (VALU pipe):
//       removes 12/17 LDS-pipe shuffles + 24 blend cndmasks per 16-step
//       group. Swap direction probed at runtime (two plausible semantics);
//       operand order selected by uniform branch; both orders verified
//       lane-exact against the R3 blended-send mapping. __has_builtin
//       fallback = R3 shfl code.
//   Reduction layout unchanged: writer lanes (lane&3)==0 hold step
//   (lane>>2)&15 over n == lane&3 (mod 4) before the xor2/xor1 butterfly.
// ---------------------------------------------------------------------------
#define SCHUNK 512
#define SDT_PITCH 544   // padded row: lifts LDS to 82KB -> exactly 1 block/CU

#if __has_builtin(__builtin_amdgcn_permlane32_swap)
#define HAVE_PL32 1
__device__ __forceinline__ float pl32_fold(float x, float y) {
    u32x2_t r = __builtin_amdgcn_permlane32_swap(
        __float_as_uint(x), __float_as_uint(y), false, false);
    return __uint_as_float(r.x) + __uint_as_float(r.y);
}
#endif
#if __has_builtin(__builtin_amdgcn_permlane16_swap)
#define HAVE_PL16 1
__device__ __forceinline__ float pl16_fold(float x, float y) {
    u32x2_t r = __builtin_amdgcn_permlane16_swap(
        __float_as_uint(x), __float_as_uint(y), false, false);
    return __uint_as_float(r.x) + __uint_as_float(r.y);
}
#endif

#define GROUP16(BC, CC, BN, CN, GG)                                          \
{                                                                            \
    const float* bn_ = bc + 16 * 256;                                        \
    _Pragma("unroll")                                                        \
    for (int t = 0; t < 16; ++t) {                                           \
        BN[t] = bn_[t * 256];                                                \
        CN[t] = bn_[t * 256 + D_STATE];                                      \
    }                                                                        \
    float4 dta = *(const float4*)&sdt[(GG)];                                 \
    float4 dtb = *(const float4*)&sdt[(GG) + 4];                             \
    float4 dtc = *(const float4*)&sdt[(GG) + 8];                             \
    float4 dtd = *(const float4*)&sdt[(GG) + 12];                            \
    uint4 xr0 = *(const uint4*)&sx[(GG)];                                    \
    uint4 xr1 = *(const uint4*)&sx[(GG) + 8];                                \
    float dt16[16] = {dta.x, dta.y, dta.z, dta.w, dtb.x, dtb.y, dtb.z, dtb.w,\
                      dtc.x, dtc.y, dtc.z, dtc.w, dtd.x, dtd.y, dtd.z, dtd.w};\
    float xf[16];                                                            \
    xf[0]  = __uint_as_float(xr0.x << 16); xf[1]  = __uint_as_float(xr0.x & 0xffff0000u); \
    xf[2]  = __uint_as_float(xr0.y << 16); xf[3]  = __uint_as_float(xr0.y & 0xffff0000u); \
    xf[4]  = __uint_as_float(xr0.z << 16); xf[5]  = __uint_as_float(xr0.z & 0xffff0000u); \
    xf[6]  = __uint_as_float(xr0.w << 16); xf[7]  = __uint_as_float(xr0.w & 0xffff0000u); \
    xf[8]  = __uint_as_float(xr1.x << 16); xf[9]  = __uint_as_float(xr1.x & 0xffff0000u); \
    xf[10] = __uint_as_float(xr1.y << 16); xf[11] = __uint_as_float(xr1.y & 0xffff0000u); \
    xf[12] = __uint_as_float(xr1.z << 16); xf[13] = __uint_as_float(xr1.z & 0xffff0000u); \
    xf[14] = __uint_as_float(xr1.w << 16); xf[15] = __uint_as_float(xr1.w & 0xffff0000u); \
    float pr[16];                                                            \
    _Pragma("unroll")                                                        \
    for (int t = 0; t < 16; ++t) {                                           \
        float a = __builtin_amdgcn_exp2f(dt16[t] * An2);                     \
        h = fmaf(h, a, (dt16[t] * xf[t]) * BC[t]);                           \
        pr[t] = h * CC[t];                                                   \
    }                                                                        \
    FOLD_STAGE1;                                                             \
    FOLD_STAGE2;                                                             \
    _Pragma("unroll")                                                        \
    for (int t = 0; t < 2; ++t) {       /* fold xor8: 4 -> 2 */              \
        float send = (lane & 8) ? pr[t] : pr[t + 2];                         \
        float recv = __shfl_xor(send, 8);                                    \
        pr[t] = ((lane & 8) ? pr[t + 2] : pr[t]) + recv;                     \
    }                                                                        \
    {                                   /* fold xor4: 2 -> 1 */              \
        float send = (lane & 4) ? pr[0] : pr[1];                             \
        float recv = __shfl_xor(send, 4);                                    \
        pr[0] = ((lane & 4) ? pr[1] : pr[0]) + recv;                         \
    }                                                                        \
    pr[0] += __shfl_xor(pr[0], 2);      /* butterfly over 4 n-residues */    \
    pr[0] += __shfl_xor(pr[0], 1);                                           \
    if ((lane & 3) == 0) {              /* 16 writer lanes, step (lane>>2)&15 */ \
        int t0 = (GG) + myt16;                                               \
        float xv = bf2f(sx[t0]);                                             \
        float zv = sz[t0];                                                   \
        zrow[cbase + t0] = fmaf(Dd, xv, pr[0]) * zv;                         \
    }                                                                        \
    bc += 16 * 256;                                                          \
}

#ifdef HAVE_PL32
#define FOLD_STAGE1                                                          \
    if (dir32) {                                                             \
        _Pragma("unroll")                                                    \
        for (int t = 0; t < 8; ++t) pr[t] = pl32_fold(pr[t + 8], pr[t]);     \
    } else {                                                                 \
        _Pragma("unroll")                                                    \
        for (int t = 0; t < 8; ++t) pr[t] = pl32_fold(pr[t], pr[t + 8]);     \
    }
#else
#define FOLD_STAGE1                                                          \
    _Pragma("unroll")                                                        \
    for (int t = 0; t < 8; ++t) {                                            \
        float send = (lane & 32) ? pr[t] : pr[t + 8];                        \
        float recv = __shfl_xor(send, 32);                                   \
        pr[t] = ((lane & 32) ? pr[t + 8] : pr[t]) + recv;                    \
    }
#endif

#ifdef HAVE_PL16
#define FOLD_STAGE2                                                          \
    if (dir16) {                                                             \
        _Pragma("unroll")                                                    \
        for (int t = 0; t < 4; ++t) pr[t] = pl16_fold(pr[t + 4], pr[t]);     \
    } else {                                                                 \
        _Pragma("unroll")                                                    \
        for (int t = 0; t < 4; ++t) pr[t] = pl16_fold(pr[t], pr[t + 4]);     \
    }
#else
#define FOLD_STAGE2                                                          \
    _Pragma("unroll")                                                        \
    for (int t = 0; t < 4; ++t) {                                            \
        float send = (lane & 16) ? pr[t] : pr[t + 4];                        \
        float recv = __shfl_xor(send, 16);                                   \
        pr[t] = ((lane & 16) ? pr[t + 4] : pr[t]) + recv;                    \
    }
#endif

__global__ __launch_bounds__(1024) void scan_seq_kernel(
    const float* __restrict__ dtT,           // [2048][8192] fp32
    const unsigned short* __restrict__ xcT16,// [2048][8192] bf16
    const float* __restrict__ xdbl,          // [8192+16][256] fp32 (B@+128, C@+192)
    float* __restrict__ zyT,                 // [2048][8192]: silu(z) in, y out
    const float* __restrict__ A_log,         // [2048][64]
    const float* __restrict__ Dp)            // [2048]
{
    __shared__ __align__(16) float s_dt[16][SDT_PITCH];        // 34 KB (padded)
    __shared__ __align__(16) unsigned short s_x[16][SCHUNK];   // 16 KB
    __shared__ __align__(16) float s_z[16][SCHUNK];            // 32 KB
    // 82 KB/block -> exactly 1 block/CU (2x82 > 160), 16 waves/CU

    const int tid  = threadIdx.x;
    const int wid  = tid >> 6;              // 0..15
    const int lane = tid & 63;
    const int bi   = blockIdx.x;            // 0..255 (== CU); bi&1 == xcd&1
    const int b    = bi & 1;                // same batch per XCD -> shared B/C
    const int d    = (bi >> 1) * 16 + wid;

    const size_t rowbase = (size_t)d * BL + (size_t)b * L_SEQ;
    const float An2 = -__expf(A_log[d * D_STATE + lane]) * 1.44269504f;
    const float Dd  = Dp[d];

    // permlane swap-direction probes (uniform, once)
#ifdef HAVE_PL32
    bool dir32;
    {
        u32x2_t r = __builtin_amdgcn_permlane32_swap((unsigned)lane,
                        (unsigned)lane + 1000u, false, false);
        dir32 = (__builtin_amdgcn_readfirstlane(r.x) == 1032u);
    }
#endif
#ifdef HAVE_PL16
    bool dir16;
    {
        u32x2_t r = __builtin_amdgcn_permlane16_swap((unsigned)lane,
                        (unsigned)lane + 1000u, false, false);
        dir16 = (__builtin_amdgcn_readfirstlane(r.x) == 1016u);
    }
#endif

    float* sdt = s_dt[wid];
    unsigned short* sx = s_x[wid];
    float* sz = s_z[wid];
    const float* dtrow = dtT + rowbase;
    const unsigned short* xrow = xcT16 + rowbase;
    float* zrow = zyT + rowbase;
    const int myt16 = (lane >> 2) & 15;     // step index this lane ends up with

    // prefetch chunk 0 (dt/z: 2x float4/lane = 512 f32; x: uint4/lane = 512 bf16)
    float4 pA = ((const float4*)dtrow)[lane];
    float4 pB = ((const float4*)dtrow)[lane + 64];
    uint4  pX = ((const uint4*)xrow)[lane];
    float4 pZ0 = ((const float4*)zrow)[lane];
    float4 pZ1 = ((const float4*)zrow)[lane + 64];

    // rolling B/C prefetch, ping-pong sets (pad-safe past the end: xdbl has
    // ~1 MiB of slack before the next workspace buffer)
    const float* bc = xdbl + ((size_t)b * L_SEQ) * 256 + DT_RANK + lane;
    float Bv0[16], Cv0[16], Bv1[16], Cv1[16];
#pragma unroll
    for (int t = 0; t < 16; ++t) { Bv0[t] = bc[t * 256]; Cv0[t] = bc[t * 256 + D_STATE]; }

    float h = 0.f;

    for (int c = 0; c < L_SEQ / SCHUNK; ++c) {
        // stage current chunk to this wave's private LDS slice (no barrier
        // needed for correctness: intra-wave LDS ops are in order)
        ((float4*)sdt)[lane]      = pA;
        ((float4*)sdt)[lane + 64] = pB;
        ((uint4*)sx)[lane]        = pX;
        ((float4*)sz)[lane]       = pZ0;
        ((float4*)sz)[lane + 64]  = pZ1;
        if (c < L_SEQ / SCHUNK - 1) {       // register-prefetch next chunk
            pA  = ((const float4*)(dtrow + (c + 1) * SCHUNK))[lane];
            pB  = ((const float4*)(dtrow + (c + 1) * SCHUNK))[lane + 64];
            pX  = ((const uint4*)(xrow + (c + 1) * SCHUNK))[lane];
            pZ0 = ((const float4*)(zrow + (c + 1) * SCHUNK))[lane];
            pZ1 = ((const float4*)(zrow + (c + 1) * SCHUNK))[lane + 64];
        }
        const int cbase = c * SCHUNK;

        for (int g = 0; g < SCHUNK; g += 32) {
            GROUP16(Bv0, Cv0, Bv1, Cv1, g);
            GROUP16(Bv1, Cv1, Bv0, Cv0, g + 16);
            // CU-wide rate-limiter: keeps all 16 waves within a 16KB B/C
            // window so L1 serves the shared stream. Raw barrier (no
            // waitcnt drain) -- no cross-wave data dependence exists.
            __builtin_amdgcn_s_barrier();
        }
    }
}

// ---------------------------------------------------------------------------
extern "C" void kernel_launch(void* const* d_in, const int* in_sizes, int n_in,
                              void* d_out, int out_size, void* d_ws, size_t ws_size,
                              hipStream_t stream)
{
    const float* hs        = (const float*)d_in[0];  // [8192][1024]
    const float* in_proj_w = (const float*)d_in[1];  // [4096][1024]
    const float* conv_w    = (const float*)d_in[2];  // [2048][4]
    const float* conv_b    = (const float*)d_in[3];  // [2048]
    const float* x_proj_w  = (const float*)d_in[4];  // [256][2048]
    const float* dt_proj_w = (const float*)d_in[5];  // [2048][128]
    const float* dt_proj_b = (const float*)d_in[6];  // [2048]
    const float* A_log     = (const float*)d_in[7];  // [2048][64]
    const float* Dp        = (const float*)d_in[8];  // [2048]
    const float* out_proj_w= (const float*)d_in[9];  // [1024][2048]
    float* out = (float*)d_out;                      // [8192][1024]

    // workspace map (MiB offsets; peak ~177.5 MiB):
    //  S0 @0   : xT fp32 (64) -> xc16 bf16 (32) @0 -> dtT fp32 (64) @0
    //  S1 @64  : zT fp32 (64)  (scan writes y in place)
    //  S2 @128 : W1_16 (8)@128 + hs16 (16)@136 -> xcT16 bf16 (32)@128 -> y16 (32)@128
    //  tail    : xdbl fp32 (8+pad)@160, xdbl16 (2)@169, Wx16 (1)@171,
    //            Wdt16 (.5)@172, Wo16 (4)@173  (end 177)
    char* ws = (char*)d_ws;
    const size_t MiB = 1024 * 1024;
    float*          xT    = (float*)(ws);
    unsigned short* xc16  = (unsigned short*)(ws);
    float*          dtT   = (float*)(ws);
    float*          zT    = (float*)(ws + 64 * MiB);
    unsigned short* W1_16 = (unsigned short*)(ws + 128 * MiB);
    unsigned short* hs16  = (unsigned short*)(ws + 136 * MiB);
    unsigned short* xcT16 = (unsigned short*)(ws + 128 * MiB);
    unsigned short* y16   = (unsigned short*)(ws + 128 * MiB);
    float*          xdbl  = (float*)(ws + 160 * MiB);   // 8 MiB + >=16-row pad
    unsigned short* xdbl16= (unsigned short*)(ws + 169 * MiB);
    unsigned short* Wx16  = (unsigned short*)(ws + 171 * MiB);
    unsigned short* Wdt16 = (unsigned short*)(ws + 172 * MiB);
    unsigned short* Wo16  = (unsigned short*)(ws + 173 * MiB);

    dim3 blk(256);

    // bf16 conversions
    cvt_f32_bf16<<<8192, blk, 0, stream>>>(hs, hs16, 2097152);
    cvt_f32_bf16<<<4096, blk, 0, stream>>>(in_proj_w, W1_16, 1048576);
    cvt_f32_bf16<<<512, blk, 0, stream>>>(x_proj_w, Wx16, 131072);
    cvt_f32_bf16<<<256, blk, 0, stream>>>(dt_proj_w, Wdt16, 65536);
    cvt_f32_bf16<<<2048, blk, 0, stream>>>(out_proj_w, Wo16, 524288);

    // 1) xT[d][m] = W1x . hs^T   (M=2048, N=8192, K=1024)
    gemm_bf16<<<dim3(64, 16), blk, 0, stream>>>(
        W1_16, D_MODEL, hs16, D_MODEL, xT, BL, D_MODEL, nullptr, 0);

    // 2) zT[d][m] = silu(W1z . hs^T)
    gemm_bf16<<<dim3(64, 16), blk, 0, stream>>>(
        W1_16 + (size_t)D_INNER * D_MODEL, D_MODEL, hs16, D_MODEL,
        zT, BL, D_MODEL, nullptr, 2);

    // 3) xcT16 = bf16(silu(conv(xT) + b))
    conv_silu_kernel<<<(D_INNER * (BL / 4)) / 256, blk, 0, stream>>>(
        xT, conv_w, conv_b, xcT16);

    // 4) xc16[m][d] = transpose(xcT16)
    transpose_bf16<<<dim3(BL / 32, D_INNER / 32), blk, 0, stream>>>(
        xcT16, BL, xc16, D_INNER);

    // 5) xdbl[m][256] = xc . x_proj^T   (M=8192, N=256, K=2048)
    gemm_bf16<<<dim3(2, 64), blk, 0, stream>>>(
        xc16, D_INNER, Wx16, D_INNER, xdbl, 256, D_INNER, nullptr, 0);

    // 6) xdbl16 = bf16(xdbl[:, :128])
    cvt_dtpart<<<1024, blk, 0, stream>>>(xdbl, xdbl16);

    // 7) dtT[d][m] = softplus(Wdt . xdbl_dt^T + b[d])  (M=2048, N=8192, K=128)
    gemm_bf16<<<dim3(64, 16), blk, 0, stream>>>(
        Wdt16, DT_RANK, xdbl16, DT_RANK, dtT, BL, DT_RANK, dt_proj_b, 1);

    // 8) single-pass scan: 1 wave per (b,d), 16 waves/block, 1 block/CU
    scan_seq_kernel<<<256, dim3(1024), 0, stream>>>(
        dtT, xcT16, xdbl, zT, A_log, Dp);

    // 9) y16[m][d] = bf16(transpose(zT))
    transpose_f32_bf16<<<dim3(BL / 32, D_INNER / 32), blk, 0, stream>>>(
        zT, BL, y16, D_INNER);

    // 10) out = y . out_proj^T   (M=8192, N=1024, K=2048)
    gemm_bf16<<<dim3(8, 64), blk, 0, stream>>>(
        y16, D_INNER, Wo16, D_INNER, out, D_MODEL, D_INNER, nullptr, 0);
}

// Round 8
// 886.050 us; speedup vs baseline: 1.1077x; 1.1077x over previous
//
#include <hip/hip_runtime.h>
#include <math.h>

// Problem constants (fixed by the reference)
#define B_SZ 2
#define L_SEQ 4096
#define D_MODEL 1024
#define D_INNER 2048
#define D_STATE 64
#define DT_RANK 128
#define BL (B_SZ * L_SEQ)          // 8192 tokens

#define AS1 __attribute__((address_space(1)))
#define AS3 __attribute__((address_space(3)))

typedef __attribute__((ext_vector_type(8))) short bf16x8_t;  // 8 bf16 = 4 VGPRs
typedef __attribute__((ext_vector_type(4))) float f32x4_t;
typedef __attribute__((ext_vector_type(2))) unsigned int u32x2_t;

__device__ __forceinline__ unsigned short f2bf(float f) {
    unsigned int u = __float_as_uint(f);
    u = (u + 0x7FFFu + ((u >> 16) & 1u)) >> 16;   // RNE
    return (unsigned short)u;
}
__device__ __forceinline__ float bf2f(unsigned short h) {
    return __uint_as_float(((unsigned int)h) << 16);
}

// ---------------------------------------------------------------------------
// fp32 -> bf16 bulk convert (n4 = count of float4 groups)
// ---------------------------------------------------------------------------
__global__ __launch_bounds__(256) void cvt_f32_bf16(
    const float* __restrict__ in, unsigned short* __restrict__ out, int n4)
{
    int i = blockIdx.x * 256 + threadIdx.x;
    if (i >= n4) return;
    float4 v = ((const float4*)in)[i];
    ushort4 o;
    o.x = f2bf(v.x); o.y = f2bf(v.y); o.z = f2bf(v.z); o.w = f2bf(v.w);
    ((ushort4*)out)[i] = o;
}

// xdbl[:, :128] (fp32, row stride 256) -> packed bf16 [8192][128]
__global__ __launch_bounds__(256) void cvt_dtpart(
    const float* __restrict__ xdbl, unsigned short* __restrict__ out)
{
    int i = blockIdx.x * 256 + threadIdx.x;   // 0 .. 8192*32-1
    int m = i >> 5, c = i & 31;
    float4 v = *(const float4*)(xdbl + (size_t)m * 256 + c * 4);
    ushort4 o;
    o.x = f2bf(v.x); o.y = f2bf(v.y); o.z = f2bf(v.z); o.w = f2bf(v.w);
    ((ushort4*)(out))[(size_t)m * 32 + c] = o;
}

// ---------------------------------------------------------------------------
// bf16 MFMA GEMM: C[m][n] = act( sum_k A[m][k]*B[n][k] [+ bias[m]] )
// ---------------------------------------------------------------------------
__global__ __launch_bounds__(256) void gemm_bf16(
    const unsigned short* __restrict__ A, int lda,
    const unsigned short* __restrict__ B, int ldb,
    float* __restrict__ C, int ldc, int K,
    const float* __restrict__ bias, int act)
{
    __shared__ unsigned short As[128 * 32];   // [row][k] linear, no pad
    __shared__ unsigned short Bs[128 * 32];

    const int tid = threadIdx.x;
    const int w = tid >> 6, lane = tid & 63;
    const int bm = blockIdx.y * 128, bn = blockIdx.x * 128;
    const int wm = (w & 1) * 64, wn = (w >> 1) * 64;

    f32x4_t acc[4][4];
#pragma unroll
    for (int i = 0; i < 4; ++i)
#pragma unroll
        for (int j = 0; j < 4; ++j) acc[i][j] = (f32x4_t){0.f, 0.f, 0.f, 0.f};

    const int srow = lane >> 2;
    const int scol = (lane & 3) * 8;
    const unsigned short* Ag0 = A + (size_t)(bm + w * 16 + srow) * lda + scol;
    const unsigned short* Ag1 = A + (size_t)(bm + 64 + w * 16 + srow) * lda + scol;
    const unsigned short* Bg0 = B + (size_t)(bn + w * 16 + srow) * ldb + scol;
    const unsigned short* Bg1 = B + (size_t)(bn + 64 + w * 16 + srow) * ldb + scol;
    unsigned short* la0 = &As[(w * 16) * 32];
    unsigned short* la1 = &As[(64 + w * 16) * 32];
    unsigned short* lb0 = &Bs[(w * 16) * 32];
    unsigned short* lb1 = &Bs[(64 + w * 16) * 32];

    const int fr = lane & 15;
    const int fk = (lane >> 4) * 8;

    for (int k0 = 0; k0 < K; k0 += 32) {
        __syncthreads();
        __builtin_amdgcn_global_load_lds((const AS1 void*)(Ag0 + k0), (AS3 void*)la0, 16, 0, 0);
        __builtin_amdgcn_global_load_lds((const AS1 void*)(Ag1 + k0), (AS3 void*)la1, 16, 0, 0);
        __builtin_amdgcn_global_load_lds((const AS1 void*)(Bg0 + k0), (AS3 void*)lb0, 16, 0, 0);
        __builtin_amdgcn_global_load_lds((const AS1 void*)(Bg1 + k0), (AS3 void*)lb1, 16, 0, 0);
        __syncthreads();

        bf16x8_t af[4], bfr[4];
#pragma unroll
        for (int i = 0; i < 4; ++i)
            af[i] = *(const bf16x8_t*)&As[(wm + i * 16 + fr) * 32 + fk];
#pragma unroll
        for (int j = 0; j < 4; ++j)
            bfr[j] = *(const bf16x8_t*)&Bs[(wn + j * 16 + fr) * 32 + fk];
#pragma unroll
        for (int i = 0; i < 4; ++i)
#pragma unroll
            for (int j = 0; j < 4; ++j)
                acc[i][j] = __builtin_amdgcn_mfma_f32_16x16x32_bf16(
                    af[i], bfr[j], acc[i][j], 0, 0, 0);
    }

    const int erow = (lane >> 4) * 4;
    const int ecol = lane & 15;
#pragma unroll
    for (int i = 0; i < 4; ++i) {
        int gr0 = bm + wm + i * 16 + erow;
#pragma unroll
        for (int j = 0; j < 4; ++j) {
            int gc = bn + wn + j * 16 + ecol;
#pragma unroll
            for (int r = 0; r < 4; ++r) {
                float v = acc[i][j][r];
                if (act == 1) {
                    float t = v + bias[gr0 + r];
                    v = (t > 20.f) ? t : log1pf(__expf(t));
                } else if (act == 2) {
                    v = v / (1.f + __expf(-v));
                }
                C[(size_t)(gr0 + r) * ldc + gc] = v;
            }
        }
    }
}

// ---------------------------------------------------------------------------
// causal depthwise conv (k=4) + bias + silu on [d][m] layout, bf16 output.
// ---------------------------------------------------------------------------
__global__ __launch_bounds__(256) void conv_silu_kernel(
    const float* __restrict__ xT,     // [2048][8192] fp32
    const float* __restrict__ w,      // [2048][4]
    const float* __restrict__ bias,   // [2048]
    unsigned short* __restrict__ xcT16) // [2048][8192] bf16
{
    int gid = blockIdx.x * blockDim.x + threadIdx.x;  // 0 .. 2048*2048-1
    int d = gid >> 11;
    int c4 = gid & 2047;
    int m0 = c4 * 4;
    int l0 = m0 & (L_SEQ - 1);

    const float* row = xT + (size_t)d * BL;
    float4 v = *(const float4*)(row + m0);
    float4 p;
    if (l0 == 0) { p.x = p.y = p.z = p.w = 0.f; }
    else         { p = *(const float4*)(row + m0 - 4); }

    float4 wv = ((const float4*)w)[d];
    float bb = bias[d];
    float e[4];
    e[0] = bb + wv.x * p.y + wv.y * p.z + wv.z * p.w + wv.w * v.x;
    e[1] = bb + wv.x * p.z + wv.y * p.w + wv.z * v.x + wv.w * v.y;
    e[2] = bb + wv.x * p.w + wv.y * v.x + wv.z * v.y + wv.w * v.z;
    e[3] = bb + wv.x * v.x + wv.y * v.y + wv.z * v.z + wv.w * v.w;
    ushort4 o;
    o.x = f2bf(e[0] / (1.f + __expf(-e[0])));
    o.y = f2bf(e[1] / (1.f + __expf(-e[1])));
    o.z = f2bf(e[2] / (1.f + __expf(-e[2])));
    o.w = f2bf(e[3] / (1.f + __expf(-e[3])));
    ((ushort4*)(xcT16 + (size_t)d * BL))[c4] = o;
}

// ---------------------------------------------------------------------------
// 32x32 tiled transposes (coalesced both sides)
// ---------------------------------------------------------------------------
__global__ __launch_bounds__(256) void transpose_f32_bf16(
    const float* __restrict__ in, int ldin,
    unsigned short* __restrict__ out, int ldout)
{
    __shared__ float tl[32][33];
    int r0 = blockIdx.y * 32, c0 = blockIdx.x * 32;
    int tx = threadIdx.x & 31, ty = threadIdx.x >> 5;
#pragma unroll
    for (int k = 0; k < 4; ++k)
        tl[ty + 8 * k][tx] = in[(size_t)(r0 + ty + 8 * k) * ldin + c0 + tx];
    __syncthreads();
#pragma unroll
    for (int k = 0; k < 4; ++k)
        out[(size_t)(c0 + ty + 8 * k) * ldout + r0 + tx] = f2bf(tl[tx][ty + 8 * k]);
}

__global__ __launch_bounds__(256) void transpose_bf16(
    const unsigned short* __restrict__ in, int ldin,
    unsigned short* __restrict__ out, int ldout)
{
    __shared__ unsigned short tl[32][33];
    int r0 = blockIdx.y * 32, c0 = blockIdx.x * 32;
    int tx = threadIdx.x & 31, ty = threadIdx.x >> 5;
#pragma unroll
    for (int k = 0; k < 4; ++k)
        tl[ty + 8 * k][tx] = in[(size_t)(r0 + ty + 8 * k) * ldin + c0 + tx];
    __syncthreads();
#pragma unroll
    for (int k = 0; k < 4; ++k)
        out[(size_t)(c0 + ty + 8 * k) * ldout + r0 + tx] = tl[tx][ty + 8 * k];
}

// ---------------------------------------------------------------------------
// Single-pass selective scan v4: ONE WAVE per (b,d); 8 waves/block sharing
// one batch's B/C stream via cooperative async LDS staging.
//   R5 post-mortem: VGPR_Count=64 proved the per-wave 16-deep B/C register
//   prefetch never existed (compiler sank the loads) -> inner loop eats L2
//   latency per group + 64-bit addr VALU per load. Fix: all 8 waves share b,
//   so B/C is staged ONCE per block into LDS with global_load_lds,
//   double-buffered in 32-step windows (T3 2-phase: issue STAGE early,
//   compute current buf, ONE __syncthreads per window -- staging has the
//   whole window ~800cy to land, so the barrier drain is ~free).
//   Inner-loop B/C becomes imm-offset ds_read_b32 (1 shared addr VGPR,
//   zero VALU). z restored to R2 read-before-write (load hoisted to group
//   start) -> full-line-warm stores, WRITE back to ~67MB.
//   Folds: permlane32/16 swaps (HW-verified R5) + shfl xor8/4 + butterfly.
//   Config: 512 blocks x 512 thr; LDS 56KB -> exactly 2 blocks/CU (16
//   waves/CU, grid fits in one round, balanced); __launch_bounds__(512,4)
//   caps VGPR at 128.
// ---------------------------------------------------------------------------
#define SCHUNK 512
#define WSTEPS 32     // B/C window

#if __has_builtin(__builtin_amdgcn_permlane32_swap)
#define HAVE_PL32 1
__device__ __forceinline__ float pl32_fold(float x, float y) {
    u32x2_t r = __builtin_amdgcn_permlane32_swap(
        __float_as_uint(x), __float_as_uint(y), false, false);
    return __uint_as_float(r.x) + __uint_as_float(r.y);
}
#endif
#if __has_builtin(__builtin_amdgcn_permlane16_swap)
#define HAVE_PL16 1
__device__ __forceinline__ float pl16_fold(float x, float y) {
    u32x2_t r = __builtin_amdgcn_permlane16_swap(
        __float_as_uint(x), __float_as_uint(y), false, false);
    return __uint_as_float(r.x) + __uint_as_float(r.y);
}
#endif

#ifdef HAVE_PL32
#define FOLD_STAGE1                                                          \
    if (dir32) {                                                             \
        _Pragma("unroll")                                                    \
        for (int t = 0; t < 8; ++t) pr[t] = pl32_fold(pr[t + 8], pr[t]);     \
    } else {                                                                 \
        _Pragma("unroll")                                                    \
        for (int t = 0; t < 8; ++t) pr[t] = pl32_fold(pr[t], pr[t + 8]);     \
    }
#else
#define FOLD_STAGE1                                                          \
    _Pragma("unroll")                                                        \
    for (int t = 0; t < 8; ++t) {                                            \
        float send = (lane & 32) ? pr[t] : pr[t + 8];                        \
        float recv = __shfl_xor(send, 32);                                   \
        pr[t] = ((lane & 32) ? pr[t + 8] : pr[t]) + recv;                    \
    }
#endif

#ifdef HAVE_PL16
#define FOLD_STAGE2                                                          \
    if (dir16) {                                                             \
        _Pragma("unroll")                                                    \
        for (int t = 0; t < 4; ++t) pr[t] = pl16_fold(pr[t + 4], pr[t]);     \
    } else {                                                                 \
        _Pragma("unroll")                                                    \
        for (int t = 0; t < 4; ++t) pr[t] = pl16_fold(pr[t], pr[t + 4]);     \
    }
#else
#define FOLD_STAGE2                                                          \
    _Pragma("unroll")                                                        \
    for (int t = 0; t < 4; ++t) {                                            \
        float send = (lane & 16) ? pr[t] : pr[t + 4];                        \
        float recv = __shfl_xor(send, 16);                                   \
        pr[t] = ((lane & 16) ? pr[t + 4] : pr[t]) + recv;                    \
    }
#endif

// Cooperative async stage of window W's B/C (32 steps x 128 floats) into
// s_bc[DB]. Each wave issues 2 global_load_lds; lanes 0-31 cover one step
// row (32 x 16B = 512B), lanes 32-63 the next (LDS dest = uniform base +
// lane*16, matching rows r*16+wid*2 and +1).
#define STAGE_BC(W, DB)                                                      \
{                                                                            \
    const unsigned t0_ = (unsigned)(W) * WSTEPS;                             \
    _Pragma("unroll")                                                        \
    for (int r_ = 0; r_ < 2; ++r_) {                                         \
        const int sl_ = r_ * 16 + wid * 2;                                   \
        const float* src_ = xdbl + (size_t)(bL + t0_ + sl_ + (lane >> 5)) * 256 \
                            + DT_RANK + (lane & 31) * 4;                     \
        __builtin_amdgcn_global_load_lds((const AS1 void*)src_,              \
            (AS3 void*)&s_bc[DB][sl_][0], 16, 0, 0);                         \
    }                                                                        \
}

#define GROUP16(GG2)                                                         \
{                                                                            \
    const int gp = gpos + (GG2);        /* step base within chunk */         \
    const int zi = cbase + gp + myt16;  /* absolute step for writer lane */  \
    float zv = 0.f;                                                          \
    if ((lane & 3) == 0) zv = zrow[zi];   /* hoisted: one group of cover */  \
    float Bv[16], Cv[16];                                                    \
    _Pragma("unroll")                                                        \
    for (int t = 0; t < 16; ++t) {                                           \
        Bv[t] = sbcw[((GG2) + t) * 128 + lane];                              \
        Cv[t] = sbcw[((GG2) + t) * 128 + 64 + lane];                         \
    }                                                                        \
    float4 dta = *(const float4*)&sdt[gp];                                   \
    float4 dtb = *(const float4*)&sdt[gp + 4];                               \
    float4 dtc = *(const float4*)&sdt[gp + 8];                               \
    float4 dtd = *(const float4*)&sdt[gp + 12];                              \
    uint4 xr0 = *(const uint4*)&sx[gp];                                      \
    uint4 xr1 = *(const uint4*)&sx[gp + 8];                                  \
    float dt16[16] = {dta.x, dta.y, dta.z, dta.w, dtb.x, dtb.y, dtb.z, dtb.w,\
                      dtc.x, dtc.y, dtc.z, dtc.w, dtd.x, dtd.y, dtd.z, dtd.w};\
    float xf[16];                                                            \
    xf[0]  = __uint_as_float(xr0.x << 16); xf[1]  = __uint_as_float(xr0.x & 0xffff0000u); \
    xf[2]  = __uint_as_float(xr0.y << 16); xf[3]  = __uint_as_float(xr0.y & 0xffff0000u); \
    xf[4]  = __uint_as_float(xr0.z << 16); xf[5]  = __uint_as_float(xr0.z & 0xffff0000u); \
    xf[6]  = __uint_as_float(xr0.w << 16); xf[7]  = __uint_as_float(xr0.w & 0xffff0000u); \
    xf[8]  = __uint_as_float(xr1.x << 16); xf[9]  = __uint_as_float(xr1.x & 0xffff0000u); \
    xf[10] = __uint_as_float(xr1.y << 16); xf[11] = __uint_as_float(xr1.y & 0xffff0000u); \
    xf[12] = __uint_as_float(xr1.z << 16); xf[13] = __uint_as_float(xr1.z & 0xffff0000u); \
    xf[14] = __uint_as_float(xr1.w << 16); xf[15] = __uint_as_float(xr1.w & 0xffff0000u); \
    float pr[16];                                                            \
    _Pragma("unroll")                                                        \
    for (int t = 0; t < 16; ++t) {                                           \
        float a = __builtin_amdgcn_exp2f(dt16[t] * An2);                     \
        h = fmaf(h, a, (dt16[t] * xf[t]) * Bv[t]);                           \
        pr[t] = h * Cv[t];                                                   \
    }                                                                        \
    FOLD_STAGE1;                                                             \
    FOLD_STAGE2;                                                             \
    _Pragma("unroll")                                                        \
    for (int t = 0; t < 2; ++t) {       /* fold xor8: 4 -> 2 */              \
        float send = (lane & 8) ? pr[t] : pr[t + 2];                         \
        float recv = __shfl_xor(send, 8);                                    \
        pr[t] = ((lane & 8) ? pr[t + 2] : pr[t]) + recv;                     \
    }                                                                        \
    {                                   /* fold xor4: 2 -> 1 */              \
        float send = (lane & 4) ? pr[0] : pr[1];                             \
        float recv = __shfl_xor(send, 4);                                    \
        pr[0] = ((lane & 4) ? pr[1] : pr[0]) + recv;                         \
    }                                                                        \
    pr[0] += __shfl_xor(pr[0], 2);      /* butterfly over 4 n-residues */    \
    pr[0] += __shfl_xor(pr[0], 1);                                           \
    if ((lane & 3) == 0) {              /* 16 writer lanes, step (lane>>2)&15 */ \
        float xv = bf2f(sx[gp + myt16]);                                     \
        zrow[zi] = fmaf(Dd, xv, pr[0]) * zv;                                 \
    }                                                                        \
}

__global__ __launch_bounds__(512, 4) void scan_seq_kernel(
    const float* __restrict__ dtT,           // [2048][8192] fp32
    const unsigned short* __restrict__ xcT16,// [2048][8192] bf16
    const float* __restrict__ xdbl,          // [8192][256] fp32 (B@+128, C@+192)
    float* __restrict__ zyT,                 // [2048][8192]: silu(z) in, y out
    const float* __restrict__ A_log,         // [2048][64]
    const float* __restrict__ Dp)            // [2048]
{
    __shared__ __align__(16) float s_dt[8][SCHUNK];           // 16 KB
    __shared__ __align__(16) unsigned short s_x[8][SCHUNK];   // 8 KB
    __shared__ __align__(16) float s_bc[2][WSTEPS][128];      // 32 KB (shared B/C)
    // 56 KB/block -> exactly 2 blocks/CU, 16 waves/CU, 512 blocks = 1 round

    const int tid  = threadIdx.x;
    const int wid  = tid >> 6;              // 0..7
    const int lane = tid & 63;
    const int bi   = blockIdx.x;            // 0..511; bi&1 constant per XCD
    const int b    = bi & 1;                // all 8 waves share b -> shared B/C
    const int d    = (bi >> 1) * 8 + wid;
    const int bL   = b * L_SEQ;

    const size_t rowbase = (size_t)d * BL + (size_t)bL;
    const float An2 = -__expf(A_log[d * D_STATE + lane]) * 1.44269504f;
    const float Dd  = Dp[d];

    // permlane swap-direction probes (uniform, once; HW-verified in R5)
#ifdef HAVE_PL32
    bool dir32;
    {
        u32x2_t r = __builtin_amdgcn_permlane32_swap((unsigned)lane,
                        (unsigned)lane + 1000u, false, false);
        dir32 = (__builtin_amdgcn_readfirstlane(r.x) == 1032u);
    }
#endif
#ifdef HAVE_PL16
    bool dir16;
    {
        u32x2_t r = __builtin_amdgcn_permlane16_swap((unsigned)lane,
                        (unsigned)lane + 1000u, false, false);
        dir16 = (__builtin_amdgcn_readfirstlane(r.x) == 1016u);
    }
#endif

    float* sdt = s_dt[wid];
    unsigned short* sx = s_x[wid];
    const float* dtrow = dtT + rowbase;
    const unsigned short* xrow = xcT16 + rowbase;
    float* zrow = zyT + rowbase;
    const int myt16 = (lane >> 2) & 15;     // step index this lane ends up with

    // prefetch chunk 0 (dt: 2x float4/lane = 512 f32; x: uint4/lane = 512 bf16)
    float4 pA = ((const float4*)dtrow)[lane];
    float4 pB = ((const float4*)dtrow)[lane + 64];
    uint4  pX = ((const uint4*)xrow)[lane];

    float h = 0.f;
    int buf = 0;

    STAGE_BC(0, 0);                          // prologue: window 0 -> buf 0
    __syncthreads();

    for (int c = 0; c < L_SEQ / SCHUNK; ++c) {
        // stage current chunk's dt/x to this wave's private LDS slice
        ((float4*)sdt)[lane]      = pA;
        ((float4*)sdt)[lane + 64] = pB;
        ((uint4*)sx)[lane]        = pX;
        if (c < L_SEQ / SCHUNK - 1) {       // register-prefetch next chunk
            pA = ((const float4*)(dtrow + (c + 1) * SCHUNK))[lane];
            pB = ((const float4*)(dtrow + (c + 1) * SCHUNK))[lane + 64];
            pX = ((const uint4*)(xrow + (c + 1) * SCHUNK))[lane];
        }
        const int cbase = c * SCHUNK;

        for (int wd = 0; wd < SCHUNK / WSTEPS; ++wd) {
            const int wglob = c * (SCHUNK / WSTEPS) + wd;
            if (wglob + 1 < L_SEQ / WSTEPS)  // issue next window's staging EARLY
                STAGE_BC(wglob + 1, buf ^ 1);
            const int gpos = wd * WSTEPS;
            const float* sbcw = &s_bc[buf][0][0];
            GROUP16(0);
            GROUP16(16);
            __syncthreads();                 // staging had a full window to land
            buf ^= 1;
        }
    }
}

// ---------------------------------------------------------------------------
extern "C" void kernel_launch(void* const* d_in, const int* in_sizes, int n_in,
                              void* d_out, int out_size, void* d_ws, size_t ws_size,
                              hipStream_t stream)
{
    const float* hs        = (const float*)d_in[0];  // [8192][1024]
    const float* in_proj_w = (const float*)d_in[1];  // [4096][1024]
    const float* conv_w    = (const float*)d_in[2];  // [2048][4]
    const float* conv_b    = (const float*)d_in[3];  // [2048]
    const float* x_proj_w  = (const float*)d_in[4];  // [256][2048]
    const float* dt_proj_w = (const float*)d_in[5];  // [2048][128]
    const float* dt_proj_b = (const float*)d_in[6];  // [2048]
    const float* A_log     = (const float*)d_in[7];  // [2048][64]
    const float* Dp        = (const float*)d_in[8];  // [2048]
    const float* out_proj_w= (const float*)d_in[9];  // [1024][2048]
    float* out = (float*)d_out;                      // [8192][1024]

    // workspace map (MiB offsets; peak ~177.5 MiB):
    //  S0 @0   : xT fp32 (64) -> xc16 bf16 (32) @0 -> dtT fp32 (64) @0
    //  S1 @64  : zT fp32 (64)  (scan writes y in place)
    //  S2 @128 : W1_16 (8)@128 + hs16 (16)@136 -> xcT16 bf16 (32)@128 -> y16 (32)@128
    //  tail    : xdbl fp32 (8)@160, xdbl16 (2)@169, Wx16 (1)@171,
    //            Wdt16 (.5)@172, Wo16 (4)@173  (end 177)
    char* ws = (char*)d_ws;
    const size_t MiB = 1024 * 1024;
    float*          xT    = (float*)(ws);
    unsigned short* xc16  = (unsigned short*)(ws);
    float*          dtT   = (float*)(ws);
    float*          zT    = (float*)(ws + 64 * MiB);
    unsigned short* W1_16 = (unsigned short*)(ws + 128 * MiB);
    unsigned short* hs16  = (unsigned short*)(ws + 136 * MiB);
    unsigned short* xcT16 = (unsigned short*)(ws + 128 * MiB);
    unsigned short* y16   = (unsigned short*)(ws + 128 * MiB);
    float*          xdbl  = (float*)(ws + 160 * MiB);
    unsigned short* xdbl16= (unsigned short*)(ws + 169 * MiB);
    unsigned short* Wx16  = (unsigned short*)(ws + 171 * MiB);
    unsigned short* Wdt16 = (unsigned short*)(ws + 172 * MiB);
    unsigned short* Wo16  = (unsigned short*)(ws + 173 * MiB);

    dim3 blk(256);

    // bf16 conversions
    cvt_f32_bf16<<<8192, blk, 0, stream>>>(hs, hs16, 2097152);
    cvt_f32_bf16<<<4096, blk, 0, stream>>>(in_proj_w, W1_16, 1048576);
    cvt_f32_bf16<<<512, blk, 0, stream>>>(x_proj_w, Wx16, 131072);
    cvt_f32_bf16<<<256, blk, 0, stream>>>(dt_proj_w, Wdt16, 65536);
    cvt_f32_bf16<<<2048, blk, 0, stream>>>(out_proj_w, Wo16, 524288);

    // 1) xT[d][m] = W1x . hs^T   (M=2048, N=8192, K=1024)
    gemm_bf16<<<dim3(64, 16), blk, 0, stream>>>(
        W1_16, D_MODEL, hs16, D_MODEL, xT, BL, D_MODEL, nullptr, 0);

    // 2) zT[d][m] = silu(W1z . hs^T)
    gemm_bf16<<<dim3(64, 16), blk, 0, stream>>>(
        W1_16 + (size_t)D_INNER * D_MODEL, D_MODEL, hs16, D_MODEL,
        zT, BL, D_MODEL, nullptr, 2);

    // 3) xcT16 = bf16(silu(conv(xT) + b))
    conv_silu_kernel<<<(D_INNER * (BL / 4)) / 256, blk, 0, stream>>>(
        xT, conv_w, conv_b, xcT16);

    // 4) xc16[m][d] = transpose(xcT16)
    transpose_bf16<<<dim3(BL / 32, D_INNER / 32), blk, 0, stream>>>(
        xcT16, BL, xc16, D_INNER);

    // 5) xdbl[m][256] = xc . x_proj^T   (M=8192, N=256, K=2048)
    gemm_bf16<<<dim3(2, 64), blk, 0, stream>>>(
        xc16, D_INNER, Wx16, D_INNER, xdbl, 256, D_INNER, nullptr, 0);

    // 6) xdbl16 = bf16(xdbl[:, :128])
    cvt_dtpart<<<1024, blk, 0, stream>>>(xdbl, xdbl16);

    // 7) dtT[d][m] = softplus(Wdt . xdbl_dt^T + b[d])  (M=2048, N=8192, K=128)
    gemm_bf16<<<dim3(64, 16), blk, 0, stream>>>(
        Wdt16, DT_RANK, xdbl16, DT_RANK, dtT, BL, DT_RANK, dt_proj_b, 1);

    // 8) single-pass scan: 1 wave per (b,d), 8 waves/block, shared B/C LDS
    scan_seq_kernel<<<512, dim3(512), 0, stream>>>(
        dtT, xcT16, xdbl, zT, A_log, Dp);

    // 9) y16[m][d] = bf16(transpose(zT))
    transpose_f32_bf16<<<dim3(BL / 32, D_INNER / 32), blk, 0, stream>>>(
        zT, BL, y16, D_INNER);

    // 10) out = y . out_proj^T   (M=8192, N=1024, K=2048)
    gemm_bf16<<<dim3(8, 64), blk, 0, stream>>>(
        y16, D_INNER, Wo16, D_INNER, out, D_MODEL, D_INNER, nullptr, 0);
}

// Round 9
// 862.818 us; speedup vs baseline: 1.1375x; 1.0269x over previous
//
#include <hip/hip_runtime.h>
#include <math.h>

// Problem constants (fixed by the reference)
#define B_SZ 2
#define L_SEQ 4096
#define D_MODEL 1024
#define D_INNER 2048
#define D_STATE 64
#define DT_RANK 128
#define BL (B_SZ * L_SEQ)          // 8192 tokens

#define AS1 __attribute__((address_space(1)))
#define AS3 __attribute__((address_space(3)))

typedef __attribute__((ext_vector_type(8))) short bf16x8_t;  // 8 bf16 = 4 VGPRs
typedef __attribute__((ext_vector_type(4))) float f32x4_t;
typedef __attribute__((ext_vector_type(2))) unsigned int u32x2_t;

__device__ __forceinline__ unsigned short f2bf(float f) {
    unsigned int u = __float_as_uint(f);
    u = (u + 0x7FFFu + ((u >> 16) & 1u)) >> 16;   // RNE
    return (unsigned short)u;
}
__device__ __forceinline__ float bf2f(unsigned short h) {
    return __uint_as_float(((unsigned int)h) << 16);
}

// ---------------------------------------------------------------------------
// fp32 -> bf16 bulk convert (n4 = count of float4 groups)
// ---------------------------------------------------------------------------
__global__ __launch_bounds__(256) void cvt_f32_bf16(
    const float* __restrict__ in, unsigned short* __restrict__ out, int n4)
{
    int i = blockIdx.x * 256 + threadIdx.x;
    if (i >= n4) return;
    float4 v = ((const float4*)in)[i];
    ushort4 o;
    o.x = f2bf(v.x); o.y = f2bf(v.y); o.z = f2bf(v.z); o.w = f2bf(v.w);
    ((ushort4*)out)[i] = o;
}

// xdbl[:, :128] (fp32, row stride 256) -> packed bf16 [8192][128]
__global__ __launch_bounds__(256) void cvt_dtpart(
    const float* __restrict__ xdbl, unsigned short* __restrict__ out)
{
    int i = blockIdx.x * 256 + threadIdx.x;   // 0 .. 8192*32-1
    int m = i >> 5, c = i & 31;
    float4 v = *(const float4*)(xdbl + (size_t)m * 256 + c * 4);
    ushort4 o;
    o.x = f2bf(v.x); o.y = f2bf(v.y); o.z = f2bf(v.z); o.w = f2bf(v.w);
    ((ushort4*)(out))[(size_t)m * 32 + c] = o;
}

// ---------------------------------------------------------------------------
// bf16 MFMA GEMM: C[m][n] = act( sum_k A[m][k]*B[n][k] [+ bias[m]] )
// ---------------------------------------------------------------------------
__global__ __launch_bounds__(256) void gemm_bf16(
    const unsigned short* __restrict__ A, int lda,
    const unsigned short* __restrict__ B, int ldb,
    float* __restrict__ C, int ldc, int K,
    const float* __restrict__ bias, int act)
{
    __shared__ unsigned short As[128 * 32];   // [row][k] linear, no pad
    __shared__ unsigned short Bs[128 * 32];

    const int tid = threadIdx.x;
    const int w = tid >> 6, lane = tid & 63;
    const int bm = blockIdx.y * 128, bn = blockIdx.x * 128;
    const int wm = (w & 1) * 64, wn = (w >> 1) * 64;

    f32x4_t acc[4][4];
#pragma unroll
    for (int i = 0; i < 4; ++i)
#pragma unroll
        for (int j = 0; j < 4; ++j) acc[i][j] = (f32x4_t){0.f, 0.f, 0.f, 0.f};

    const int srow = lane >> 2;
    const int scol = (lane & 3) * 8;
    const unsigned short* Ag0 = A + (size_t)(bm + w * 16 + srow) * lda + scol;
    const unsigned short* Ag1 = A + (size_t)(bm + 64 + w * 16 + srow) * lda + scol;
    const unsigned short* Bg0 = B + (size_t)(bn + w * 16 + srow) * ldb + scol;
    const unsigned short* Bg1 = B + (size_t)(bn + 64 + w * 16 + srow) * ldb + scol;
    unsigned short* la0 = &As[(w * 16) * 32];
    unsigned short* la1 = &As[(64 + w * 16) * 32];
    unsigned short* lb0 = &Bs[(w * 16) * 32];
    unsigned short* lb1 = &Bs[(64 + w * 16) * 32];

    const int fr = lane & 15;
    const int fk = (lane >> 4) * 8;

    for (int k0 = 0; k0 < K; k0 += 32) {
        __syncthreads();
        __builtin_amdgcn_global_load_lds((const AS1 void*)(Ag0 + k0), (AS3 void*)la0, 16, 0, 0);
        __builtin_amdgcn_global_load_lds((const AS1 void*)(Ag1 + k0), (AS3 void*)la1, 16, 0, 0);
        __builtin_amdgcn_global_load_lds((const AS1 void*)(Bg0 + k0), (AS3 void*)lb0, 16, 0, 0);
        __builtin_amdgcn_global_load_lds((const AS1 void*)(Bg1 + k0), (AS3 void*)lb1, 16, 0, 0);
        __syncthreads();

        bf16x8_t af[4], bfr[4];
#pragma unroll
        for (int i = 0; i < 4; ++i)
            af[i] = *(const bf16x8_t*)&As[(wm + i * 16 + fr) * 32 + fk];
#pragma unroll
        for (int j = 0; j < 4; ++j)
            bfr[j] = *(const bf16x8_t*)&Bs[(wn + j * 16 + fr) * 32 + fk];
#pragma unroll
        for (int i = 0; i < 4; ++i)
#pragma unroll
            for (int j = 0; j < 4; ++j)
                acc[i][j] = __builtin_amdgcn_mfma_f32_16x16x32_bf16(
                    af[i], bfr[j], acc[i][j], 0, 0, 0);
    }

    const int erow = (lane >> 4) * 4;
    const int ecol = lane & 15;
#pragma unroll
    for (int i = 0; i < 4; ++i) {
        int gr0 = bm + wm + i * 16 + erow;
#pragma unroll
        for (int j = 0; j < 4; ++j) {
            int gc = bn + wn + j * 16 + ecol;
#pragma unroll
            for (int r = 0; r < 4; ++r) {
                float v = acc[i][j][r];
                if (act == 1) {
                    float t = v + bias[gr0 + r];
                    v = (t > 20.f) ? t : log1pf(__expf(t));
                } else if (act == 2) {
                    v = v / (1.f + __expf(-v));
                }
                C[(size_t)(gr0 + r) * ldc + gc] = v;
            }
        }
    }
}

// ---------------------------------------------------------------------------
// causal depthwise conv (k=4) + bias + silu on [d][m] layout, bf16 output.
// ---------------------------------------------------------------------------
__global__ __launch_bounds__(256) void conv_silu_kernel(
    const float* __restrict__ xT,     // [2048][8192] fp32
    const float* __restrict__ w,      // [2048][4]
    const float* __restrict__ bias,   // [2048]
    unsigned short* __restrict__ xcT16) // [2048][8192] bf16
{
    int gid = blockIdx.x * blockDim.x + threadIdx.x;  // 0 .. 2048*2048-1
    int d = gid >> 11;
    int c4 = gid & 2047;
    int m0 = c4 * 4;
    int l0 = m0 & (L_SEQ - 1);

    const float* row = xT + (size_t)d * BL;
    float4 v = *(const float4*)(row + m0);
    float4 p;
    if (l0 == 0) { p.x = p.y = p.z = p.w = 0.f; }
    else         { p = *(const float4*)(row + m0 - 4); }

    float4 wv = ((const float4*)w)[d];
    float bb = bias[d];
    float e[4];
    e[0] = bb + wv.x * p.y + wv.y * p.z + wv.z * p.w + wv.w * v.x;
    e[1] = bb + wv.x * p.z + wv.y * p.w + wv.z * v.x + wv.w * v.y;
    e[2] = bb + wv.x * p.w + wv.y * v.x + wv.z * v.y + wv.w * v.z;
    e[3] = bb + wv.x * v.x + wv.y * v.y + wv.z * v.z + wv.w * v.w;
    ushort4 o;
    o.x = f2bf(e[0] / (1.f + __expf(-e[0])));
    o.y = f2bf(e[1] / (1.f + __expf(-e[1])));
    o.z = f2bf(e[2] / (1.f + __expf(-e[2])));
    o.w = f2bf(e[3] / (1.f + __expf(-e[3])));
    ((ushort4*)(xcT16 + (size_t)d * BL))[c4] = o;
}

// ---------------------------------------------------------------------------
// 32x32 tiled transposes (coalesced both sides)
// ---------------------------------------------------------------------------
__global__ __launch_bounds__(256) void transpose_f32_bf16(
    const float* __restrict__ in, int ldin,
    unsigned short* __restrict__ out, int ldout)
{
    __shared__ float tl[32][33];
    int r0 = blockIdx.y * 32, c0 = blockIdx.x * 32;
    int tx = threadIdx.x & 31, ty = threadIdx.x >> 5;
#pragma unroll
    for (int k = 0; k < 4; ++k)
        tl[ty + 8 * k][tx] = in[(size_t)(r0 + ty + 8 * k) * ldin + c0 + tx];
    __syncthreads();
#pragma unroll
    for (int k = 0; k < 4; ++k)
        out[(size_t)(c0 + ty + 8 * k) * ldout + r0 + tx] = f2bf(tl[tx][ty + 8 * k]);
}

__global__ __launch_bounds__(256) void transpose_bf16(
    const unsigned short* __restrict__ in, int ldin,
    unsigned short* __restrict__ out, int ldout)
{
    __shared__ unsigned short tl[32][33];
    int r0 = blockIdx.y * 32, c0 = blockIdx.x * 32;
    int tx = threadIdx.x & 31, ty = threadIdx.x >> 5;
#pragma unroll
    for (int k = 0; k < 4; ++k)
        tl[ty + 8 * k][tx] = in[(size_t)(r0 + ty + 8 * k) * ldin + c0 + tx];
    __syncthreads();
#pragma unroll
    for (int k = 0; k < 4; ++k)
        out[(size_t)(c0 + ty + 8 * k) * ldout + r0 + tx] = tl[tx][ty + 8 * k];
}

// ---------------------------------------------------------------------------
// Single-pass selective scan v5: ONE WAVE per (b,d); 8 waves/block sharing
// one batch's B/C stream via cooperative async LDS staging (R6, measured:
// FETCH 176->97MB, WRITE 175->67MB, scan 457us, VALUBusy 82.6%).
//   R8 changes (issue-bound -> cut wave-redundant VALU):
//   (1) dtx = dt*x premultiplied ONCE per chunk at staging into s_dtx
//       (f32, uniform b128 broadcast reads). Removes the per-group x-unpack
//       (16 ops) + dt*x mul (16 ops) that every lane redundantly recomputed
//       every 16 steps -- amortized ~60x by chunk staging. (R4's dtx try
//       regressed, but was bundled with s_y round-trip on a different base.)
//   (2) xor2/xor1 butterflies via DPP quad_perm (VALU pipe, 0x4E=[2,3,0,1]
//       =xor2, 0xB1=[1,0,3,2]=xor1) -- removes 2 LDS swizzles/group.
//   LDS 72KB -> still 2 blocks/CU (16 waves/CU), 512 blocks = 1 round.
// ---------------------------------------------------------------------------
#define SCHUNK 512
#define WSTEPS 32     // B/C window

#if __has_builtin(__builtin_amdgcn_permlane32_swap)
#define HAVE_PL32 1
__device__ __forceinline__ float pl32_fold(float x, float y) {
    u32x2_t r = __builtin_amdgcn_permlane32_swap(
        __float_as_uint(x), __float_as_uint(y), false, false);
    return __uint_as_float(r.x) + __uint_as_float(r.y);
}
#endif
#if __has_builtin(__builtin_amdgcn_permlane16_swap)
#define HAVE_PL16 1
__device__ __forceinline__ float pl16_fold(float x, float y) {
    u32x2_t r = __builtin_amdgcn_permlane16_swap(
        __float_as_uint(x), __float_as_uint(y), false, false);
    return __uint_as_float(r.x) + __uint_as_float(r.y);
}
#endif

#ifdef HAVE_PL32
#define FOLD_STAGE1                                                          \
    if (dir32) {                                                             \
        _Pragma("unroll")                                                    \
        for (int t = 0; t < 8; ++t) pr[t] = pl32_fold(pr[t + 8], pr[t]);     \
    } else {                                                                 \
        _Pragma("unroll")                                                    \
        for (int t = 0; t < 8; ++t) pr[t] = pl32_fold(pr[t], pr[t + 8]);     \
    }
#else
#define FOLD_STAGE1                                                          \
    _Pragma("unroll")                                                        \
    for (int t = 0; t < 8; ++t) {                                            \
        float send = (lane & 32) ? pr[t] : pr[t + 8];                        \
        float recv = __shfl_xor(send, 32);                                   \
        pr[t] = ((lane & 32) ? pr[t + 8] : pr[t]) + recv;                    \
    }
#endif

#ifdef HAVE_PL16
#define FOLD_STAGE2                                                          \
    if (dir16) {                                                             \
        _Pragma("unroll")                                                    \
        for (int t = 0; t < 4; ++t) pr[t] = pl16_fold(pr[t + 4], pr[t]);     \
    } else {                                                                 \
        _Pragma("unroll")                                                    \
        for (int t = 0; t < 4; ++t) pr[t] = pl16_fold(pr[t], pr[t + 4]);     \
    }
#else
#define FOLD_STAGE2                                                          \
    _Pragma("unroll")                                                        \
    for (int t = 0; t < 4; ++t) {                                            \
        float send = (lane & 16) ? pr[t] : pr[t + 4];                        \
        float recv = __shfl_xor(send, 16);                                   \
        pr[t] = ((lane & 16) ? pr[t + 4] : pr[t]) + recv;                    \
    }
#endif

// xor2 then xor1 butterfly on pr[0]: DPP quad_perm (stays within quads).
#if __has_builtin(__builtin_amdgcn_mov_dpp)
#define BFLY21                                                               \
    pr[0] += __int_as_float(__builtin_amdgcn_mov_dpp(                        \
                 __float_as_int(pr[0]), 0x4E, 0xF, 0xF, true));              \
    pr[0] += __int_as_float(__builtin_amdgcn_mov_dpp(                        \
                 __float_as_int(pr[0]), 0xB1, 0xF, 0xF, true));
#else
#define BFLY21                                                               \
    pr[0] += __shfl_xor(pr[0], 2);                                           \
    pr[0] += __shfl_xor(pr[0], 1);
#endif

// Cooperative async stage of window W's B/C (32 steps x 128 floats) into
// s_bc[DB]. Each wave issues 2 global_load_lds; lanes 0-31 cover one step
// row (32 x 16B = 512B), lanes 32-63 the next.
#define STAGE_BC(W, DB)                                                      \
{                                                                            \
    const unsigned t0_ = (unsigned)(W) * WSTEPS;                             \
    _Pragma("unroll")                                                        \
    for (int r_ = 0; r_ < 2; ++r_) {                                         \
        const int sl_ = r_ * 16 + wid * 2;                                   \
        const float* src_ = xdbl + (size_t)(bL + t0_ + sl_ + (lane >> 5)) * 256 \
                            + DT_RANK + (lane & 31) * 4;                     \
        __builtin_amdgcn_global_load_lds((const AS1 void*)src_,              \
            (AS3 void*)&s_bc[DB][sl_][0], 16, 0, 0);                         \
    }                                                                        \
}

#define GROUP16(GG2)                                                         \
{                                                                            \
    const int gp = gpos + (GG2);        /* step base within chunk */         \
    const int zi = cbase + gp + myt16;  /* absolute step for writer lane */  \
    float zv = 0.f;                                                          \
    if ((lane & 3) == 0) zv = zrow[zi];   /* hoisted: one group of cover */  \
    float Bv[16], Cv[16];                                                    \
    _Pragma("unroll")                                                        \
    for (int t = 0; t < 16; ++t) {                                           \
        Bv[t] = sbcw[((GG2) + t) * 128 + lane];                              \
        Cv[t] = sbcw[((GG2) + t) * 128 + 64 + lane];                         \
    }                                                                        \
    float4 dta = *(const float4*)&sdt[gp];                                   \
    float4 dtb = *(const float4*)&sdt[gp + 4];                               \
    float4 dtc = *(const float4*)&sdt[gp + 8];                               \
    float4 dtd = *(const float4*)&sdt[gp + 12];                              \
    float4 dxa = *(const float4*)&sdtx[gp];                                  \
    float4 dxb = *(const float4*)&sdtx[gp + 4];                              \
    float4 dxc = *(const float4*)&sdtx[gp + 8];                              \
    float4 dxd = *(const float4*)&sdtx[gp + 12];                             \
    float dt16[16] = {dta.x, dta.y, dta.z, dta.w, dtb.x, dtb.y, dtb.z, dtb.w,\
                      dtc.x, dtc.y, dtc.z, dtc.w, dtd.x, dtd.y, dtd.z, dtd.w};\
    float dx16[16] = {dxa.x, dxa.y, dxa.z, dxa.w, dxb.x, dxb.y, dxb.z, dxb.w,\
                      dxc.x, dxc.y, dxc.z, dxc.w, dxd.x, dxd.y, dxd.z, dxd.w};\
    float pr[16];                                                            \
    _Pragma("unroll")                                                        \
    for (int t = 0; t < 16; ++t) {                                           \
        float a = __builtin_amdgcn_exp2f(dt16[t] * An2);                     \
        h = fmaf(h, a, dx16[t] * Bv[t]);                                     \
        pr[t] = h * Cv[t];                                                   \
    }                                                                        \
    FOLD_STAGE1;                                                             \
    FOLD_STAGE2;                                                             \
    _Pragma("unroll")                                                        \
    for (int t = 0; t < 2; ++t) {       /* fold xor8: 4 -> 2 */              \
        float send = (lane & 8) ? pr[t] : pr[t + 2];                         \
        float recv = __shfl_xor(send, 8);                                    \
        pr[t] = ((lane & 8) ? pr[t + 2] : pr[t]) + recv;                     \
    }                                                                        \
    {                                   /* fold xor4: 2 -> 1 */              \
        float send = (lane & 4) ? pr[0] : pr[1];                             \
        float recv = __shfl_xor(send, 4);                                    \
        pr[0] = ((lane & 4) ? pr[1] : pr[0]) + recv;                         \
    }                                                                        \
    BFLY21;                             /* butterfly over 4 n-residues */    \
    if ((lane & 3) == 0) {              /* 16 writer lanes, step (lane>>2)&15 */ \
        float xv = bf2f(sx[gp + myt16]);                                     \
        zrow[zi] = fmaf(Dd, xv, pr[0]) * zv;                                 \
    }                                                                        \
}

__global__ __launch_bounds__(512, 4) void scan_seq_kernel(
    const float* __restrict__ dtT,           // [2048][8192] fp32
    const unsigned short* __restrict__ xcT16,// [2048][8192] bf16
    const float* __restrict__ xdbl,          // [8192][256] fp32 (B@+128, C@+192)
    float* __restrict__ zyT,                 // [2048][8192]: silu(z) in, y out
    const float* __restrict__ A_log,         // [2048][64]
    const float* __restrict__ Dp)            // [2048]
{
    __shared__ __align__(16) float s_dt[8][SCHUNK];           // 16 KB
    __shared__ __align__(16) float s_dtx[8][SCHUNK];          // 16 KB
    __shared__ __align__(16) unsigned short s_x[8][SCHUNK];   // 8 KB
    __shared__ __align__(16) float s_bc[2][WSTEPS][128];      // 32 KB (shared B/C)
    // 72 KB/block -> 2 blocks/CU, 16 waves/CU, 512 blocks = 1 round

    const int tid  = threadIdx.x;
    const int wid  = tid >> 6;              // 0..7
    const int lane = tid & 63;
    const int bi   = blockIdx.x;            // 0..511; bi&1 constant per XCD
    const int b    = bi & 1;                // all 8 waves share b -> shared B/C
    const int d    = (bi >> 1) * 8 + wid;
    const int bL   = b * L_SEQ;

    const size_t rowbase = (size_t)d * BL + (size_t)bL;
    const float An2 = -__expf(A_log[d * D_STATE + lane]) * 1.44269504f;
    const float Dd  = Dp[d];

    // permlane swap-direction probes (uniform, once; HW-verified in R5)
#ifdef HAVE_PL32
    bool dir32;
    {
        u32x2_t r = __builtin_amdgcn_permlane32_swap((unsigned)lane,
                        (unsigned)lane + 1000u, false, false);
        dir32 = (__builtin_amdgcn_readfirstlane(r.x) == 1032u);
    }
#endif
#ifdef HAVE_PL16
    bool dir16;
    {
        u32x2_t r = __builtin_amdgcn_permlane16_swap((unsigned)lane,
                        (unsigned)lane + 1000u, false, false);
        dir16 = (__builtin_amdgcn_readfirstlane(r.x) == 1016u);
    }
#endif

    float* sdt = s_dt[wid];
    float* sdtx = s_dtx[wid];
    unsigned short* sx = s_x[wid];
    const float* dtrow = dtT + rowbase;
    const unsigned short* xrow = xcT16 + rowbase;
    float* zrow = zyT + rowbase;
    const int myt16 = (lane >> 2) & 15;     // step index this lane ends up with

    // prefetch chunk 0. dt loaded in the SAME element range as x (8 elems
    // per lane): pA = elems 8*lane..+3, pB = 8*lane+4..+7, pX = 8 bf16.
    float4 pA = ((const float4*)dtrow)[2 * lane];
    float4 pB = ((const float4*)dtrow)[2 * lane + 1];
    uint4  pX = ((const uint4*)xrow)[lane];

    float h = 0.f;
    int buf = 0;

    STAGE_BC(0, 0);                          // prologue: window 0 -> buf 0
    __syncthreads();

    for (int c = 0; c < L_SEQ / SCHUNK; ++c) {
        // stage current chunk's dt/x/dtx to this wave's private LDS slice.
        // dtx = dt*x computed ONCE here (amortized over 32 groups). The
        // 16-way-conflict b128 writes at stride 32B happen once per 512
        // steps -- negligible.
        ((float4*)sdt)[2 * lane]     = pA;
        ((float4*)sdt)[2 * lane + 1] = pB;
        ((uint4*)sx)[lane]           = pX;
        float4 dxA, dxB;
        dxA.x = pA.x * __uint_as_float(pX.x << 16);
        dxA.y = pA.y * __uint_as_float(pX.x & 0xffff0000u);
        dxA.z = pA.z * __uint_as_float(pX.y << 16);
        dxA.w = pA.w * __uint_as_float(pX.y & 0xffff0000u);
        dxB.x = pB.x * __uint_as_float(pX.z << 16);
        dxB.y = pB.y * __uint_as_float(pX.z & 0xffff0000u);
        dxB.z = pB.z * __uint_as_float(pX.w << 16);
        dxB.w = pB.w * __uint_as_float(pX.w & 0xffff0000u);
        ((float4*)sdtx)[2 * lane]     = dxA;
        ((float4*)sdtx)[2 * lane + 1] = dxB;

        if (c < L_SEQ / SCHUNK - 1) {       // register-prefetch next chunk
            pA = ((const float4*)(dtrow + (c + 1) * SCHUNK))[2 * lane];
            pB = ((const float4*)(dtrow + (c + 1) * SCHUNK))[2 * lane + 1];
            pX = ((const uint4*)(xrow + (c + 1) * SCHUNK))[lane];
        }
        const int cbase = c * SCHUNK;

        for (int wd = 0; wd < SCHUNK / WSTEPS; ++wd) {
            const int wglob = c * (SCHUNK / WSTEPS) + wd;
            if (wglob + 1 < L_SEQ / WSTEPS)  // issue next window's staging EARLY
                STAGE_BC(wglob + 1, buf ^ 1);
            const int gpos = wd * WSTEPS;
            const float* sbcw = &s_bc[buf][0][0];
            GROUP16(0);
            GROUP16(16);
            __syncthreads();                 // staging had a full window to land
            buf ^= 1;
        }
    }
}

// ---------------------------------------------------------------------------
extern "C" void kernel_launch(void* const* d_in, const int* in_sizes, int n_in,
                              void* d_out, int out_size, void* d_ws, size_t ws_size,
                              hipStream_t stream)
{
    const float* hs        = (const float*)d_in[0];  // [8192][1024]
    const float* in_proj_w = (const float*)d_in[1];  // [4096][1024]
    const float* conv_w    = (const float*)d_in[2];  // [2048][4]
    const float* conv_b    = (const float*)d_in[3];  // [2048]
    const float* x_proj_w  = (const float*)d_in[4];  // [256][2048]
    const float* dt_proj_w = (const float*)d_in[5];  // [2048][128]
    const float* dt_proj_b = (const float*)d_in[6];  // [2048]
    const float* A_log     = (const float*)d_in[7];  // [2048][64]
    const float* Dp        = (const float*)d_in[8];  // [2048]
    const float* out_proj_w= (const float*)d_in[9];  // [1024][2048]
    float* out = (float*)d_out;                      // [8192][1024]

    // workspace map (MiB offsets; peak ~177.5 MiB):
    //  S0 @0   : xT fp32 (64) -> xc16 bf16 (32) @0 -> dtT fp32 (64) @0
    //  S1 @64  : zT fp32 (64)  (scan writes y in place)
    //  S2 @128 : W1_16 (8)@128 + hs16 (16)@136 -> xcT16 bf16 (32)@128 -> y16 (32)@128
    //  tail    : xdbl fp32 (8)@160, xdbl16 (2)@169, Wx16 (1)@171,
    //            Wdt16 (.5)@172, Wo16 (4)@173  (end 177)
    char* ws = (char*)d_ws;
    const size_t MiB = 1024 * 1024;
    float*          xT    = (float*)(ws);
    unsigned short* xc16  = (unsigned short*)(ws);
    float*          dtT   = (float*)(ws);
    float*          zT    = (float*)(ws + 64 * MiB);
    unsigned short* W1_16 = (unsigned short*)(ws + 128 * MiB);
    unsigned short* hs16  = (unsigned short*)(ws + 136 * MiB);
    unsigned short* xcT16 = (unsigned short*)(ws + 128 * MiB);
    unsigned short* y16   = (unsigned short*)(ws + 128 * MiB);
    float*          xdbl  = (float*)(ws + 160 * MiB);
    unsigned short* xdbl16= (unsigned short*)(ws + 169 * MiB);
    unsigned short* Wx16  = (unsigned short*)(ws + 171 * MiB);
    unsigned short* Wdt16 = (unsigned short*)(ws + 172 * MiB);
    unsigned short* Wo16  = (unsigned short*)(ws + 173 * MiB);

    dim3 blk(256);

    // bf16 conversions
    cvt_f32_bf16<<<8192, blk, 0, stream>>>(hs, hs16, 2097152);
    cvt_f32_bf16<<<4096, blk, 0, stream>>>(in_proj_w, W1_16, 1048576);
    cvt_f32_bf16<<<512, blk, 0, stream>>>(x_proj_w, Wx16, 131072);
    cvt_f32_bf16<<<256, blk, 0, stream>>>(dt_proj_w, Wdt16, 65536);
    cvt_f32_bf16<<<2048, blk, 0, stream>>>(out_proj_w, Wo16, 524288);

    // 1) xT[d][m] = W1x . hs^T   (M=2048, N=8192, K=1024)
    gemm_bf16<<<dim3(64, 16), blk, 0, stream>>>(
        W1_16, D_MODEL, hs16, D_MODEL, xT, BL, D_MODEL, nullptr, 0);

    // 2) zT[d][m] = silu(W1z . hs^T)
    gemm_bf16<<<dim3(64, 16), blk, 0, stream>>>(
        W1_16 + (size_t)D_INNER * D_MODEL, D_MODEL, hs16, D_MODEL,
        zT, BL, D_MODEL, nullptr, 2);

    // 3) xcT16 = bf16(silu(conv(xT) + b))
    conv_silu_kernel<<<(D_INNER * (BL / 4)) / 256, blk, 0, stream>>>(
        xT, conv_w, conv_b, xcT16);

    // 4) xc16[m][d] = transpose(xcT16)
    transpose_bf16<<<dim3(BL / 32, D_INNER / 32), blk, 0, stream>>>(
        xcT16, BL, xc16, D_INNER);

    // 5) xdbl[m][256] = xc . x_proj^T   (M=8192, N=256, K=2048)
    gemm_bf16<<<dim3(2, 64), blk, 0, stream>>>(
        xc16, D_INNER, Wx16, D_INNER, xdbl, 256, D_INNER, nullptr, 0);

    // 6) xdbl16 = bf16(xdbl[:, :128])
    cvt_dtpart<<<1024, blk, 0, stream>>>(xdbl, xdbl16);

    // 7) dtT[d][m] = softplus(Wdt . xdbl_dt^T + b[d])  (M=2048, N=8192, K=128)
    gemm_bf16<<<dim3(64, 16), blk, 0, stream>>>(
        Wdt16, DT_RANK, xdbl16, DT_RANK, dtT, BL, DT_RANK, dt_proj_b, 1);

    // 8) single-pass scan: 1 wave per (b,d), 8 waves/block, shared B/C LDS
    scan_seq_kernel<<<512, dim3(512), 0, stream>>>(
        dtT, xcT16, xdbl, zT, A_log, Dp);

    // 9) y16[m][d] = bf16(transpose(zT))
    transpose_f32_bf16<<<dim3(BL / 32, D_INNER / 32), blk, 0, stream>>>(
        zT, BL, y16, D_INNER);

    // 10) out = y . out_proj^T   (M=8192, N=1024, K=2048)
    gemm_bf16<<<dim3(8, 64), blk, 0, stream>>>(
        y16, D_INNER, Wo16, D_INNER, out, D_MODEL, D_INNER, nullptr, 0);
}

// Round 10
// 847.365 us; speedup vs baseline: 1.1582x; 1.0182x over previous
//
#include <hip/hip_runtime.h>
#include <math.h>

// Problem constants (fixed by the reference)
#define B_SZ 2
#define L_SEQ 4096
#define D_MODEL 1024
#define D_INNER 2048
#define D_STATE 64
#define DT_RANK 128
#define BL (B_SZ * L_SEQ)          // 8192 tokens

#define AS1 __attribute__((address_space(1)))
#define AS3 __attribute__((address_space(3)))

typedef __attribute__((ext_vector_type(8))) short bf16x8_t;  // 8 bf16 = 4 VGPRs
typedef __attribute__((ext_vector_type(4))) float f32x4_t;
typedef __attribute__((ext_vector_type(2))) unsigned int u32x2_t;

__device__ __forceinline__ unsigned short f2bf(float f) {
    unsigned int u = __float_as_uint(f);
    u = (u + 0x7FFFu + ((u >> 16) & 1u)) >> 16;   // RNE
    return (unsigned short)u;
}
__device__ __forceinline__ float bf2f(unsigned short h) {
    return __uint_as_float(((unsigned int)h) << 16);
}

// ---------------------------------------------------------------------------
// fp32 -> bf16 bulk convert (n4 = count of float4 groups)
// ---------------------------------------------------------------------------
__global__ __launch_bounds__(256) void cvt_f32_bf16(
    const float* __restrict__ in, unsigned short* __restrict__ out, int n4)
{
    int i = blockIdx.x * 256 + threadIdx.x;
    if (i >= n4) return;
    float4 v = ((const float4*)in)[i];
    ushort4 o;
    o.x = f2bf(v.x); o.y = f2bf(v.y); o.z = f2bf(v.z); o.w = f2bf(v.w);
    ((ushort4*)out)[i] = o;
}

// xdbl[:, :128] (fp32, row stride 256) -> packed bf16 [8192][128]
__global__ __launch_bounds__(256) void cvt_dtpart(
    const float* __restrict__ xdbl, unsigned short* __restrict__ out)
{
    int i = blockIdx.x * 256 + threadIdx.x;   // 0 .. 8192*32-1
    int m = i >> 5, c = i & 31;
    float4 v = *(const float4*)(xdbl + (size_t)m * 256 + c * 4);
    ushort4 o;
    o.x = f2bf(v.x); o.y = f2bf(v.y); o.z = f2bf(v.z); o.w = f2bf(v.w);
    ((ushort4*)(out))[(size_t)m * 32 + c] = o;
}

// B/C repack: bc2[t>>2][n][t&3] = xdbl[t][128+n]  (n=0..127; B at n<64, C at
// n>=64). Makes 4 consecutive steps' B (or C) for one lane a contiguous 16B
// quad -> scan reads b128 instead of 4x b32. 4MB r + 4MB w, ~4us.
__global__ __launch_bounds__(256) void repack_bc(
    const float* __restrict__ xdbl,   // [8192][256]
    float* __restrict__ bc2)          // [2048][128][4]
{
    int i = blockIdx.x * 256 + threadIdx.x;   // 0 .. 262143
    int t4 = i >> 7, n = i & 127;
    const float* s = xdbl + (size_t)(t4 * 4) * 256 + 128 + n;
    float4 o;
    o.x = s[0]; o.y = s[256]; o.z = s[512]; o.w = s[768];
    ((float4*)bc2)[i] = o;
}

// ---------------------------------------------------------------------------
// bf16 MFMA GEMM: C[m][n] = act( sum_k A[m][k]*B[n][k] [+ bias[m]] )
// ---------------------------------------------------------------------------
__global__ __launch_bounds__(256) void gemm_bf16(
    const unsigned short* __restrict__ A, int lda,
    const unsigned short* __restrict__ B, int ldb,
    float* __restrict__ C, int ldc, int K,
    const float* __restrict__ bias, int act)
{
    __shared__ unsigned short As[128 * 32];   // [row][k] linear, no pad
    __shared__ unsigned short Bs[128 * 32];

    const int tid = threadIdx.x;
    const int w = tid >> 6, lane = tid & 63;
    const int bm = blockIdx.y * 128, bn = blockIdx.x * 128;
    const int wm = (w & 1) * 64, wn = (w >> 1) * 64;

    f32x4_t acc[4][4];
#pragma unroll
    for (int i = 0; i < 4; ++i)
#pragma unroll
        for (int j = 0; j < 4; ++j) acc[i][j] = (f32x4_t){0.f, 0.f, 0.f, 0.f};

    const int srow = lane >> 2;
    const int scol = (lane & 3) * 8;
    const unsigned short* Ag0 = A + (size_t)(bm + w * 16 + srow) * lda + scol;
    const unsigned short* Ag1 = A + (size_t)(bm + 64 + w * 16 + srow) * lda + scol;
    const unsigned short* Bg0 = B + (size_t)(bn + w * 16 + srow) * ldb + scol;
    const unsigned short* Bg1 = B + (size_t)(bn + 64 + w * 16 + srow) * ldb + scol;
    unsigned short* la0 = &As[(w * 16) * 32];
    unsigned short* la1 = &As[(64 + w * 16) * 32];
    unsigned short* lb0 = &Bs[(w * 16) * 32];
    unsigned short* lb1 = &Bs[(64 + w * 16) * 32];

    const int fr = lane & 15;
    const int fk = (lane >> 4) * 8;

    for (int k0 = 0; k0 < K; k0 += 32) {
        __syncthreads();
        __builtin_amdgcn_global_load_lds((const AS1 void*)(Ag0 + k0), (AS3 void*)la0, 16, 0, 0);
        __builtin_amdgcn_global_load_lds((const AS1 void*)(Ag1 + k0), (AS3 void*)la1, 16, 0, 0);
        __builtin_amdgcn_global_load_lds((const AS1 void*)(Bg0 + k0), (AS3 void*)lb0, 16, 0, 0);
        __builtin_amdgcn_global_load_lds((const AS1 void*)(Bg1 + k0), (AS3 void*)lb1, 16, 0, 0);
        __syncthreads();

        bf16x8_t af[4], bfr[4];
#pragma unroll
        for (int i = 0; i < 4; ++i)
            af[i] = *(const bf16x8_t*)&As[(wm + i * 16 + fr) * 32 + fk];
#pragma unroll
        for (int j = 0; j < 4; ++j)
            bfr[j] = *(const bf16x8_t*)&Bs[(wn + j * 16 + fr) * 32 + fk];
#pragma unroll
        for (int i = 0; i < 4; ++i)
#pragma unroll
            for (int j = 0; j < 4; ++j)
                acc[i][j] = __builtin_amdgcn_mfma_f32_16x16x32_bf16(
                    af[i], bfr[j], acc[i][j], 0, 0, 0);
    }

    const int erow = (lane >> 4) * 4;
    const int ecol = lane & 15;
#pragma unroll
    for (int i = 0; i < 4; ++i) {
        int gr0 = bm + wm + i * 16 + erow;
#pragma unroll
        for (int j = 0; j < 4; ++j) {
            int gc = bn + wn + j * 16 + ecol;
#pragma unroll
            for (int r = 0; r < 4; ++r) {
                float v = acc[i][j][r];
                if (act == 1) {
                    float t = v + bias[gr0 + r];
                    v = (t > 20.f) ? t : log1pf(__expf(t));
                } else if (act == 2) {
                    v = v / (1.f + __expf(-v));
                }
                C[(size_t)(gr0 + r) * ldc + gc] = v;
            }
        }
    }
}

// ---------------------------------------------------------------------------
// causal depthwise conv (k=4) + bias + silu on [d][m] layout, bf16 output.
// ---------------------------------------------------------------------------
__global__ __launch_bounds__(256) void conv_silu_kernel(
    const float* __restrict__ xT,     // [2048][8192] fp32
    const float* __restrict__ w,      // [2048][4]
    const float* __restrict__ bias,   // [2048]
    unsigned short* __restrict__ xcT16) // [2048][8192] bf16
{
    int gid = blockIdx.x * blockDim.x + threadIdx.x;  // 0 .. 2048*2048-1
    int d = gid >> 11;
    int c4 = gid & 2047;
    int m0 = c4 * 4;
    int l0 = m0 & (L_SEQ - 1);

    const float* row = xT + (size_t)d * BL;
    float4 v = *(const float4*)(row + m0);
    float4 p;
    if (l0 == 0) { p.x = p.y = p.z = p.w = 0.f; }
    else         { p = *(const float4*)(row + m0 - 4); }

    float4 wv = ((const float4*)w)[d];
    float bb = bias[d];
    float e[4];
    e[0] = bb + wv.x * p.y + wv.y * p.z + wv.z * p.w + wv.w * v.x;
    e[1] = bb + wv.x * p.z + wv.y * p.w + wv.z * v.x + wv.w * v.y;
    e[2] = bb + wv.x * p.w + wv.y * v.x + wv.z * v.y + wv.w * v.z;
    e[3] = bb + wv.x * v.x + wv.y * v.y + wv.z * v.z + wv.w * v.w;
    ushort4 o;
    o.x = f2bf(e[0] / (1.f + __expf(-e[0])));
    o.y = f2bf(e[1] / (1.f + __expf(-e[1])));
    o.z = f2bf(e[2] / (1.f + __expf(-e[2])));
    o.w = f2bf(e[3] / (1.f + __expf(-e[3])));
    ((ushort4*)(xcT16 + (size_t)d * BL))[c4] = o;
}

// ---------------------------------------------------------------------------
// 32x32 tiled transposes (coalesced both sides)
// ---------------------------------------------------------------------------
__global__ __launch_bounds__(256) void transpose_f32_bf16(
    const float* __restrict__ in, int ldin,
    unsigned short* __restrict__ out, int ldout)
{
    __shared__ float tl[32][33];
    int r0 = blockIdx.y * 32, c0 = blockIdx.x * 32;
    int tx = threadIdx.x & 31, ty = threadIdx.x >> 5;
#pragma unroll
    for (int k = 0; k < 4; ++k)
        tl[ty + 8 * k][tx] = in[(size_t)(r0 + ty + 8 * k) * ldin + c0 + tx];
    __syncthreads();
#pragma unroll
    for (int k = 0; k < 4; ++k)
        out[(size_t)(c0 + ty + 8 * k) * ldout + r0 + tx] = f2bf(tl[tx][ty + 8 * k]);
}

__global__ __launch_bounds__(256) void transpose_bf16(
    const unsigned short* __restrict__ in, int ldin,
    unsigned short* __restrict__ out, int ldout)
{
    __shared__ unsigned short tl[32][33];
    int r0 = blockIdx.y * 32, c0 = blockIdx.x * 32;
    int tx = threadIdx.x & 31, ty = threadIdx.x >> 5;
#pragma unroll
    for (int k = 0; k < 4; ++k)
        tl[ty + 8 * k][tx] = in[(size_t)(r0 + ty + 8 * k) * ldin + c0 + tx];
    __syncthreads();
#pragma unroll
    for (int k = 0; k < 4; ++k)
        out[(size_t)(c0 + ty + 8 * k) * ldout + r0 + tx] = tl[tx][ty + 8 * k];
}

// ---------------------------------------------------------------------------
// Single-pass selective scan v6: ONE WAVE per (b,d); 8 waves/block sharing
// one batch's B/C via double-buffered LDS windows (R6/R8 base, measured:
// 412us, VALUBusy 79%, FETCH 96MB, WRITE 67MB).
//   R9 change: B/C pre-packed in global (repack_bc) as bc2[t/4][n][t%4] so
//   the per-group B/C LDS reads become 8x ds_read_b128 (lane-stride 16B,
//   conflict-free) instead of 32x ds_read_b32. Issue-slot audit: 260
//   slots/group x4 waves ~= the 965cy/group budget (issue-saturated);
//   -24 instrs/group ~= -9%. STAGE becomes a linear 16KB window copy.
//   z loads for both groups hoisted to window top (full-group cover).
// ---------------------------------------------------------------------------
#define SCHUNK 512
#define WSTEPS 32     // B/C window

#if __has_builtin(__builtin_amdgcn_permlane32_swap)
#define HAVE_PL32 1
__device__ __forceinline__ float pl32_fold(float x, float y) {
    u32x2_t r = __builtin_amdgcn_permlane32_swap(
        __float_as_uint(x), __float_as_uint(y), false, false);
    return __uint_as_float(r.x) + __uint_as_float(r.y);
}
#endif
#if __has_builtin(__builtin_amdgcn_permlane16_swap)
#define HAVE_PL16 1
__device__ __forceinline__ float pl16_fold(float x, float y) {
    u32x2_t r = __builtin_amdgcn_permlane16_swap(
        __float_as_uint(x), __float_as_uint(y), false, false);
    return __uint_as_float(r.x) + __uint_as_float(r.y);
}
#endif

#ifdef HAVE_PL32
#define FOLD_STAGE1                                                          \
    if (dir32) {                                                             \
        _Pragma("unroll")                                                    \
        for (int t = 0; t < 8; ++t) pr[t] = pl32_fold(pr[t + 8], pr[t]);     \
    } else {                                                                 \
        _Pragma("unroll")                                                    \
        for (int t = 0; t < 8; ++t) pr[t] = pl32_fold(pr[t], pr[t + 8]);     \
    }
#else
#define FOLD_STAGE1                                                          \
    _Pragma("unroll")                                                        \
    for (int t = 0; t < 8; ++t) {                                            \
        float send = (lane & 32) ? pr[t] : pr[t + 8];                        \
        float recv = __shfl_xor(send, 32);                                   \
        pr[t] = ((lane & 32) ? pr[t + 8] : pr[t]) + recv;                    \
    }
#endif

#ifdef HAVE_PL16
#define FOLD_STAGE2                                                          \
    if (dir16) {                                                             \
        _Pragma("unroll")                                                    \
        for (int t = 0; t < 4; ++t) pr[t] = pl16_fold(pr[t + 4], pr[t]);     \
    } else {                                                                 \
        _Pragma("unroll")                                                    \
        for (int t = 0; t < 4; ++t) pr[t] = pl16_fold(pr[t], pr[t + 4]);     \
    }
#else
#define FOLD_STAGE2                                                          \
    _Pragma("unroll")                                                        \
    for (int t = 0; t < 4; ++t) {                                            \
        float send = (lane & 16) ? pr[t] : pr[t + 4];                        \
        float recv = __shfl_xor(send, 16);                                   \
        pr[t] = ((lane & 16) ? pr[t + 4] : pr[t]) + recv;                    \
    }
#endif

// xor2 then xor1 butterfly on pr[0]: DPP quad_perm (stays within quads).
#if __has_builtin(__builtin_amdgcn_mov_dpp)
#define BFLY21                                                               \
    pr[0] += __int_as_float(__builtin_amdgcn_mov_dpp(                        \
                 __float_as_int(pr[0]), 0x4E, 0xF, 0xF, true));              \
    pr[0] += __int_as_float(__builtin_amdgcn_mov_dpp(                        \
                 __float_as_int(pr[0]), 0xB1, 0xF, 0xF, true));
#else
#define BFLY21                                                               \
    pr[0] += __shfl_xor(pr[0], 2);                                           \
    pr[0] += __shfl_xor(pr[0], 1);
#endif

// Cooperative async stage of window W's packed B/C (16KB linear) into
// s_bc2[DB]. Each wave copies 2x 1KB (64 lanes x 16B); global src per-lane,
// LDS dest wave-uniform base (+lane*16 by HW).
#define STAGE_BC(W, DB)                                                      \
{                                                                            \
    const float* wbase_ = bc2 + (size_t)(bQ + 8u * (unsigned)(W)) * 512;     \
    _Pragma("unroll")                                                        \
    for (int r_ = 0; r_ < 2; ++r_) {                                         \
        const float* src_ = wbase_ + (wid * 2 + r_) * 256 + lane * 4;        \
        __builtin_amdgcn_global_load_lds((const AS1 void*)src_,              \
            (AS3 void*)&s_bc2[DB][(wid * 2 + r_) * 256], 16, 0, 0);          \
    }                                                                        \
}

#define GROUP16(GG2, ZV)                                                     \
{                                                                            \
    const int gp = gpos + (GG2);        /* step base within chunk */         \
    const int t4b = (GG2) >> 2;                                              \
    f32x4_t bv[4], cv[4];                                                    \
    _Pragma("unroll")                                                        \
    for (int a = 0; a < 4; ++a) {       /* b128: 4 steps' B (or C) per read */\
        bv[a] = *(const f32x4_t*)&sbcw[(t4b + a) * 512 + lane * 4];          \
        cv[a] = *(const f32x4_t*)&sbcw[(t4b + a) * 512 + 256 + lane * 4];    \
    }                                                                        \
    float4 dta = *(const float4*)&sdt[gp];                                   \
    float4 dtb = *(const float4*)&sdt[gp + 4];                               \
    float4 dtc = *(const float4*)&sdt[gp + 8];                               \
    float4 dtd = *(const float4*)&sdt[gp + 12];                              \
    float4 dxa = *(const float4*)&sdtx[gp];                                  \
    float4 dxb = *(const float4*)&sdtx[gp + 4];                              \
    float4 dxc = *(const float4*)&sdtx[gp + 8];                              \
    float4 dxd = *(const float4*)&sdtx[gp + 12];                             \
    float dt16[16] = {dta.x, dta.y, dta.z, dta.w, dtb.x, dtb.y, dtb.z, dtb.w,\
                      dtc.x, dtc.y, dtc.z, dtc.w, dtd.x, dtd.y, dtd.z, dtd.w};\
    float dx16[16] = {dxa.x, dxa.y, dxa.z, dxa.w, dxb.x, dxb.y, dxb.z, dxb.w,\
                      dxc.x, dxc.y, dxc.z, dxc.w, dxd.x, dxd.y, dxd.z, dxd.w};\
    float pr[16];                                                            \
    _Pragma("unroll")                                                        \
    for (int t = 0; t < 16; ++t) {                                           \
        float a_ = __builtin_amdgcn_exp2f(dt16[t] * An2);                    \
        h = fmaf(h, a_, dx16[t] * bv[t >> 2][t & 3]);                        \
        pr[t] = h * cv[t >> 2][t & 3];                                       \
    }                                                                        \
    FOLD_STAGE1;                                                             \
    FOLD_STAGE2;                                                             \
    _Pragma("unroll")                                                        \
    for (int t = 0; t < 2; ++t) {       /* fold xor8: 4 -> 2 */              \
        float send = (lane & 8) ? pr[t] : pr[t + 2];                         \
        float recv = __shfl_xor(send, 8);                                    \
        pr[t] = ((lane & 8) ? pr[t + 2] : pr[t]) + recv;                     \
    }                                                                        \
    {                                   /* fold xor4: 2 -> 1 */              \
        float send = (lane & 4) ? pr[0] : pr[1];                             \
        float recv = __shfl_xor(send, 4);                                    \
        pr[0] = ((lane & 4) ? pr[1] : pr[0]) + recv;                         \
    }                                                                        \
    BFLY21;                             /* butterfly over 4 n-residues */    \
    if ((lane & 3) == 0) {              /* 16 writer lanes, step (lane>>2)&15 */ \
        float xv = bf2f(sx[gp + myt16]);                                     \
        zrow[cbase + gp + myt16] = fmaf(Dd, xv, pr[0]) * (ZV);               \
    }                                                                        \
}

__global__ __launch_bounds__(512, 4) void scan_seq_kernel(
    const float* __restrict__ dtT,           // [2048][8192] fp32
    const unsigned short* __restrict__ xcT16,// [2048][8192] bf16
    const float* __restrict__ bc2,           // [2048][128][4] packed B/C
    float* __restrict__ zyT,                 // [2048][8192]: silu(z) in, y out
    const float* __restrict__ A_log,         // [2048][64]
    const float* __restrict__ Dp)            // [2048]
{
    __shared__ __align__(16) float s_dt[8][SCHUNK];           // 16 KB
    __shared__ __align__(16) float s_dtx[8][SCHUNK];          // 16 KB
    __shared__ __align__(16) unsigned short s_x[8][SCHUNK];   // 8 KB
    __shared__ __align__(16) float s_bc2[2][WSTEPS * 128];    // 32 KB (packed B/C)
    // 72 KB/block -> 2 blocks/CU, 16 waves/CU, 512 blocks = 1 round

    const int tid  = threadIdx.x;
    const int wid  = tid >> 6;              // 0..7
    const int lane = tid & 63;
    const int bi   = blockIdx.x;            // 0..511; bi&1 constant per XCD
    const int b    = bi & 1;                // all 8 waves share b -> shared B/C
    const int d    = (bi >> 1) * 8 + wid;
    const unsigned bQ = (unsigned)b * (L_SEQ / 4);   // t4 offset of this batch

    const size_t rowbase = (size_t)d * BL + (size_t)(b * L_SEQ);
    const float An2 = -__expf(A_log[d * D_STATE + lane]) * 1.44269504f;
    const float Dd  = Dp[d];

    // permlane swap-direction probes (uniform, once; HW-verified in R5)
#ifdef HAVE_PL32
    bool dir32;
    {
        u32x2_t r = __builtin_amdgcn_permlane32_swap((unsigned)lane,
                        (unsigned)lane + 1000u, false, false);
        dir32 = (__builtin_amdgcn_readfirstlane(r.x) == 1032u);
    }
#endif
#ifdef HAVE_PL16
    bool dir16;
    {
        u32x2_t r = __builtin_amdgcn_permlane16_swap((unsigned)lane,
                        (unsigned)lane + 1000u, false, false);
        dir16 = (__builtin_amdgcn_readfirstlane(r.x) == 1016u);
    }
#endif

    float* sdt = s_dt[wid];
    float* sdtx = s_dtx[wid];
    unsigned short* sx = s_x[wid];
    const float* dtrow = dtT + rowbase;
    const unsigned short* xrow = xcT16 + rowbase;
    float* zrow = zyT + rowbase;
    const int myt16 = (lane >> 2) & 15;     // step index this lane ends up with

    // prefetch chunk 0. dt loaded in the SAME element range as x (8 elems
    // per lane): pA = elems 8*lane..+3, pB = 8*lane+4..+7, pX = 8 bf16.
    float4 pA = ((const float4*)dtrow)[2 * lane];
    float4 pB = ((const float4*)dtrow)[2 * lane + 1];
    uint4  pX = ((const uint4*)xrow)[lane];

    float h = 0.f;
    int buf = 0;

    STAGE_BC(0, 0);                          // prologue: window 0 -> buf 0
    __syncthreads();

    for (int c = 0; c < L_SEQ / SCHUNK; ++c) {
        // stage current chunk's dt/x/dtx to this wave's private LDS slice.
        // dtx = dt*x computed ONCE here (amortized over 32 groups).
        ((float4*)sdt)[2 * lane]     = pA;
        ((float4*)sdt)[2 * lane + 1] = pB;
        ((uint4*)sx)[lane]           = pX;
        float4 dxA, dxB;
        dxA.x = pA.x * __uint_as_float(pX.x << 16);
        dxA.y = pA.y * __uint_as_float(pX.x & 0xffff0000u);
        dxA.z = pA.z * __uint_as_float(pX.y << 16);
        dxA.w = pA.w * __uint_as_float(pX.y & 0xffff0000u);
        dxB.x = pB.x * __uint_as_float(pX.z << 16);
        dxB.y = pB.y * __uint_as_float(pX.z & 0xffff0000u);
        dxB.z = pB.z * __uint_as_float(pX.w << 16);
        dxB.w = pB.w * __uint_as_float(pX.w & 0xffff0000u);
        ((float4*)sdtx)[2 * lane]     = dxA;
        ((float4*)sdtx)[2 * lane + 1] = dxB;

        if (c < L_SEQ / SCHUNK - 1) {       // register-prefetch next chunk
            pA = ((const float4*)(dtrow + (c + 1) * SCHUNK))[2 * lane];
            pB = ((const float4*)(dtrow + (c + 1) * SCHUNK))[2 * lane + 1];
            pX = ((const uint4*)(xrow + (c + 1) * SCHUNK))[lane];
        }
        const int cbase = c * SCHUNK;

        for (int wd = 0; wd < SCHUNK / WSTEPS; ++wd) {
            const int wglob = c * (SCHUNK / WSTEPS) + wd;
            if (wglob + 1 < L_SEQ / WSTEPS)  // issue next window's staging EARLY
                STAGE_BC(wglob + 1, buf ^ 1);
            const int gpos = wd * WSTEPS;
            // hoist z for both groups: full-group latency cover
            float zv0 = 0.f, zv1 = 0.f;
            if ((lane & 3) == 0) {
                zv0 = zrow[cbase + gpos + myt16];
                zv1 = zrow[cbase + gpos + 16 + myt16];
            }
            const float* sbcw = s_bc2[buf];
            GROUP16(0, zv0);
            GROUP16(16, zv1);
            __syncthreads();                 // staging had a full window to land
            buf ^= 1;
        }
    }
}

// ---------------------------------------------------------------------------
extern "C" void kernel_launch(void* const* d_in, const int* in_sizes, int n_in,
                              void* d_out, int out_size, void* d_ws, size_t ws_size,
                              hipStream_t stream)
{
    const float* hs        = (const float*)d_in[0];  // [8192][1024]
    const float* in_proj_w = (const float*)d_in[1];  // [4096][1024]
    const float* conv_w    = (const float*)d_in[2];  // [2048][4]
    const float* conv_b    = (const float*)d_in[3];  // [2048]
    const float* x_proj_w  = (const float*)d_in[4];  // [256][2048]
    const float* dt_proj_w = (const float*)d_in[5];  // [2048][128]
    const float* dt_proj_b = (const float*)d_in[6];  // [2048]
    const float* A_log     = (const float*)d_in[7];  // [2048][64]
    const float* Dp        = (const float*)d_in[8];  // [2048]
    const float* out_proj_w= (const float*)d_in[9];  // [1024][2048]
    float* out = (float*)d_out;                      // [8192][1024]

    // workspace map (MiB offsets; peak ~177.5 MiB):
    //  S0 @0   : xT fp32 (64) -> xc16 bf16 (32) @0 -> dtT fp32 (64) @0
    //  S1 @64  : zT fp32 (64)  (scan writes y in place)
    //  S2 @128 : W1_16 (8)@128 + hs16 (16)@136 -> xcT16 bf16 (32)@128 -> y16 (32)@128
    //  tail    : xdbl fp32 (8)@160, xdbl16 (2)@169 -> bc2 (4)@169 (xdbl16,
    //            Wx16, Wdt16 all dead by repack time), Wx16 (1)@171,
    //            Wdt16 (.5)@172, Wo16 (4)@173  (end 177)
    char* ws = (char*)d_ws;
    const size_t MiB = 1024 * 1024;
    float*          xT    = (float*)(ws);
    unsigned short* xc16  = (unsigned short*)(ws);
    float*          dtT   = (float*)(ws);
    float*          zT    = (float*)(ws + 64 * MiB);
    unsigned short* W1_16 = (unsigned short*)(ws + 128 * MiB);
    unsigned short* hs16  = (unsigned short*)(ws + 136 * MiB);
    unsigned short* xcT16 = (unsigned short*)(ws + 128 * MiB);
    unsigned short* y16   = (unsigned short*)(ws + 128 * MiB);
    float*          xdbl  = (float*)(ws + 160 * MiB);
    unsigned short* xdbl16= (unsigned short*)(ws + 169 * MiB);
    float*          bc2   = (float*)(ws + 169 * MiB);   // reuses dead region
    unsigned short* Wx16  = (unsigned short*)(ws + 171 * MiB);
    unsigned short* Wdt16 = (unsigned short*)(ws + 172 * MiB);
    unsigned short* Wo16  = (unsigned short*)(ws + 173 * MiB);

    dim3 blk(256);

    // bf16 conversions
    cvt_f32_bf16<<<8192, blk, 0, stream>>>(hs, hs16, 2097152);
    cvt_f32_bf16<<<4096, blk, 0, stream>>>(in_proj_w, W1_16, 1048576);
    cvt_f32_bf16<<<512, blk, 0, stream>>>(x_proj_w, Wx16, 131072);
    cvt_f32_bf16<<<256, blk, 0, stream>>>(dt_proj_w, Wdt16, 65536);
    cvt_f32_bf16<<<2048, blk, 0, stream>>>(out_proj_w, Wo16, 524288);

    // 1) xT[d][m] = W1x . hs^T   (M=2048, N=8192, K=1024)
    gemm_bf16<<<dim3(64, 16), blk, 0, stream>>>(
        W1_16, D_MODEL, hs16, D_MODEL, xT, BL, D_MODEL, nullptr, 0);

    // 2) zT[d][m] = silu(W1z . hs^T)
    gemm_bf16<<<dim3(64, 16), blk, 0, stream>>>(
        W1_16 + (size_t)D_INNER * D_MODEL, D_MODEL, hs16, D_MODEL,
        zT, BL, D_MODEL, nullptr, 2);

    // 3) xcT16 = bf16(silu(conv(xT) + b))
    conv_silu_kernel<<<(D_INNER * (BL / 4)) / 256, blk, 0, stream>>>(
        xT, conv_w, conv_b, xcT16);

    // 4) xc16[m][d] = transpose(xcT16)
    transpose_bf16<<<dim3(BL / 32, D_INNER / 32), blk, 0, stream>>>(
        xcT16, BL, xc16, D_INNER);

    // 5) xdbl[m][256] = xc . x_proj^T   (M=8192, N=256, K=2048)
    gemm_bf16<<<dim3(2, 64), blk, 0, stream>>>(
        xc16, D_INNER, Wx16, D_INNER, xdbl, 256, D_INNER, nullptr, 0);

    // 6) xdbl16 = bf16(xdbl[:, :128])
    cvt_dtpart<<<1024, blk, 0, stream>>>(xdbl, xdbl16);

    // 7) dtT[d][m] = softplus(Wdt . xdbl_dt^T + b[d])  (M=2048, N=8192, K=128)
    gemm_bf16<<<dim3(64, 16), blk, 0, stream>>>(
        Wdt16, DT_RANK, xdbl16, DT_RANK, dtT, BL, DT_RANK, dt_proj_b, 1);

    // 7b) pack B/C for b128 LDS reads in the scan
    repack_bc<<<1024, blk, 0, stream>>>(xdbl, bc2);

    // 8) single-pass scan: 1 wave per (b,d), 8 waves/block, packed B/C LDS
    scan_seq_kernel<<<512, dim3(512), 0, stream>>>(
        dtT, xcT16, bc2, zT, A_log, Dp);

    // 9) y16[m][d] = bf16(transpose(zT))
    transpose_f32_bf16<<<dim3(BL / 32, D_INNER / 32), blk, 0, stream>>>(
        zT, BL, y16, D_INNER);

    // 10) out = y . out_proj^T   (M=8192, N=1024, K=2048)
    gemm_bf16<<<dim3(8, 64), blk, 0, stream>>>(
        y16, D_INNER, Wo16, D_INNER, out, D_MODEL, D_INNER, nullptr, 0);
}

// Round 11
// 819.069 us; speedup vs baseline: 1.1982x; 1.0345x over previous
//
#include <hip/hip_runtime.h>
#include <math.h>

// Problem constants (fixed by the reference)
#define B_SZ 2
#define L_SEQ 4096
#define D_MODEL 1024
#define D_INNER 2048
#define D_STATE 64
#define DT_RANK 128
#define BL (B_SZ * L_SEQ)          // 8192 tokens

#define AS1 __attribute__((address_space(1)))
#define AS3 __attribute__((address_space(3)))

typedef __attribute__((ext_vector_type(8))) short bf16x8_t;  // 8 bf16 = 4 VGPRs
typedef __attribute__((ext_vector_type(4))) float f32x4_t;
typedef __attribute__((ext_vector_type(2))) float f32x2_t;
typedef __attribute__((ext_vector_type(2))) unsigned int u32x2_t;

__device__ __forceinline__ unsigned short f2bf(float f) {
    unsigned int u = __float_as_uint(f);
    u = (u + 0x7FFFu + ((u >> 16) & 1u)) >> 16;   // RNE
    return (unsigned short)u;
}
__device__ __forceinline__ float bf2f(unsigned short h) {
    return __uint_as_float(((unsigned int)h) << 16);
}

// ---------------------------------------------------------------------------
// fp32 -> bf16 bulk convert (n4 = count of float4 groups)
// ---------------------------------------------------------------------------
__global__ __launch_bounds__(256) void cvt_f32_bf16(
    const float* __restrict__ in, unsigned short* __restrict__ out, int n4)
{
    int i = blockIdx.x * 256 + threadIdx.x;
    if (i >= n4) return;
    float4 v = ((const float4*)in)[i];
    ushort4 o;
    o.x = f2bf(v.x); o.y = f2bf(v.y); o.z = f2bf(v.z); o.w = f2bf(v.w);
    ((ushort4*)out)[i] = o;
}

// xdbl[:, :128] (fp32, row stride 256) -> packed bf16 [8192][128]
__global__ __launch_bounds__(256) void cvt_dtpart(
    const float* __restrict__ xdbl, unsigned short* __restrict__ out)
{
    int i = blockIdx.x * 256 + threadIdx.x;   // 0 .. 8192*32-1
    int m = i >> 5, c = i & 31;
    float4 v = *(const float4*)(xdbl + (size_t)m * 256 + c * 4);
    ushort4 o;
    o.x = f2bf(v.x); o.y = f2bf(v.y); o.z = f2bf(v.z); o.w = f2bf(v.w);
    ((ushort4*)(out))[(size_t)m * 32 + c] = o;
}

// B/C repack: bc2[t>>2][n][t&3] = xdbl[t][128+n]  (n=0..127; B at n<64, C at
// n>=64). Makes 4 consecutive steps' B (or C) for one lane a contiguous 16B
// quad -> scan reads b128 instead of 4x b32. 4MB r + 4MB w, ~4us.
__global__ __launch_bounds__(256) void repack_bc(
    const float* __restrict__ xdbl,   // [8192][256]
    float* __restrict__ bc2)          // [2048][128][4]
{
    int i = blockIdx.x * 256 + threadIdx.x;   // 0 .. 262143
    int t4 = i >> 7, n = i & 127;
    const float* s = xdbl + (size_t)(t4 * 4) * 256 + 128 + n;
    float4 o;
    o.x = s[0]; o.y = s[256]; o.z = s[512]; o.w = s[768];
    ((float4*)bc2)[i] = o;
}

// ---------------------------------------------------------------------------
// bf16 MFMA GEMM: C[m][n] = act( sum_k A[m][k]*B[n][k] [+ bias[m]] )
// ---------------------------------------------------------------------------
__global__ __launch_bounds__(256) void gemm_bf16(
    const unsigned short* __restrict__ A, int lda,
    const unsigned short* __restrict__ B, int ldb,
    float* __restrict__ C, int ldc, int K,
    const float* __restrict__ bias, int act)
{
    __shared__ unsigned short As[128 * 32];   // [row][k] linear, no pad
    __shared__ unsigned short Bs[128 * 32];

    const int tid = threadIdx.x;
    const int w = tid >> 6, lane = tid & 63;
    const int bm = blockIdx.y * 128, bn = blockIdx.x * 128;
    const int wm = (w & 1) * 64, wn = (w >> 1) * 64;

    f32x4_t acc[4][4];
#pragma unroll
    for (int i = 0; i < 4; ++i)
#pragma unroll
        for (int j = 0; j < 4; ++j) acc[i][j] = (f32x4_t){0.f, 0.f, 0.f, 0.f};

    const int srow = lane >> 2;
    const int scol = (lane & 3) * 8;
    const unsigned short* Ag0 = A + (size_t)(bm + w * 16 + srow) * lda + scol;
    const unsigned short* Ag1 = A + (size_t)(bm + 64 + w * 16 + srow) * lda + scol;
    const unsigned short* Bg0 = B + (size_t)(bn + w * 16 + srow) * ldb + scol;
    const unsigned short* Bg1 = B + (size_t)(bn + 64 + w * 16 + srow) * ldb + scol;
    unsigned short* la0 = &As[(w * 16) * 32];
    unsigned short* la1 = &As[(64 + w * 16) * 32];
    unsigned short* lb0 = &Bs[(w * 16) * 32];
    unsigned short* lb1 = &Bs[(64 + w * 16) * 32];

    const int fr = lane & 15;
    const int fk = (lane >> 4) * 8;

    for (int k0 = 0; k0 < K; k0 += 32) {
        __syncthreads();
        __builtin_amdgcn_global_load_lds((const AS1 void*)(Ag0 + k0), (AS3 void*)la0, 16, 0, 0);
        __builtin_amdgcn_global_load_lds((const AS1 void*)(Ag1 + k0), (AS3 void*)la1, 16, 0, 0);
        __builtin_amdgcn_global_load_lds((const AS1 void*)(Bg0 + k0), (AS3 void*)lb0, 16, 0, 0);
        __builtin_amdgcn_global_load_lds((const AS1 void*)(Bg1 + k0), (AS3 void*)lb1, 16, 0, 0);
        __syncthreads();

        bf16x8_t af[4], bfr[4];
#pragma unroll
        for (int i = 0; i < 4; ++i)
            af[i] = *(const bf16x8_t*)&As[(wm + i * 16 + fr) * 32 + fk];
#pragma unroll
        for (int j = 0; j < 4; ++j)
            bfr[j] = *(const bf16x8_t*)&Bs[(wn + j * 16 + fr) * 32 + fk];
#pragma unroll
        for (int i = 0; i < 4; ++i)
#pragma unroll
            for (int j = 0; j < 4; ++j)
                acc[i][j] = __builtin_amdgcn_mfma_f32_16x16x32_bf16(
                    af[i], bfr[j], acc[i][j], 0, 0, 0);
    }

    const int erow = (lane >> 4) * 4;
    const int ecol = lane & 15;
#pragma unroll
    for (int i = 0; i < 4; ++i) {
        int gr0 = bm + wm + i * 16 + erow;
#pragma unroll
        for (int j = 0; j < 4; ++j) {
            int gc = bn + wn + j * 16 + ecol;
#pragma unroll
            for (int r = 0; r < 4; ++r) {
                float v = acc[i][j][r];
                if (act == 1) {
                    float t = v + bias[gr0 + r];
                    v = (t > 20.f) ? t : log1pf(__expf(t));
                } else if (act == 2) {
                    v = v / (1.f + __expf(-v));
                }
                C[(size_t)(gr0 + r) * ldc + gc] = v;
            }
        }
    }
}

// ---------------------------------------------------------------------------
// causal depthwise conv (k=4) + bias + silu on [d][m] layout, bf16 output.
// ---------------------------------------------------------------------------
__global__ __launch_bounds__(256) void conv_silu_kernel(
    const float* __restrict__ xT,     // [2048][8192] fp32
    const float* __restrict__ w,      // [2048][4]
    const float* __restrict__ bias,   // [2048]
    unsigned short* __restrict__ xcT16) // [2048][8192] bf16
{
    int gid = blockIdx.x * blockDim.x + threadIdx.x;  // 0 .. 2048*2048-1
    int d = gid >> 11;
    int c4 = gid & 2047;
    int m0 = c4 * 4;
    int l0 = m0 & (L_SEQ - 1);

    const float* row = xT + (size_t)d * BL;
    float4 v = *(const float4*)(row + m0);
    float4 p;
    if (l0 == 0) { p.x = p.y = p.z = p.w = 0.f; }
    else         { p = *(const float4*)(row + m0 - 4); }

    float4 wv = ((const float4*)w)[d];
    float bb = bias[d];
    float e[4];
    e[0] = bb + wv.x * p.y + wv.y * p.z + wv.z * p.w + wv.w * v.x;
    e[1] = bb + wv.x * p.z + wv.y * p.w + wv.z * v.x + wv.w * v.y;
    e[2] = bb + wv.x * p.w + wv.y * v.x + wv.z * v.y + wv.w * v.z;
    e[3] = bb + wv.x * v.x + wv.y * v.y + wv.z * v.z + wv.w * v.w;
    ushort4 o;
    o.x = f2bf(e[0] / (1.f + __expf(-e[0])));
    o.y = f2bf(e[1] / (1.f + __expf(-e[1])));
    o.z = f2bf(e[2] / (1.f + __expf(-e[2])));
    o.w = f2bf(e[3] / (1.f + __expf(-e[3])));
    ((ushort4*)(xcT16 + (size_t)d * BL))[c4] = o;
}

// ---------------------------------------------------------------------------
// 32x32 tiled transposes (coalesced both sides)
// ---------------------------------------------------------------------------
__global__ __launch_bounds__(256) void transpose_f32_bf16(
    const float* __restrict__ in, int ldin,
    unsigned short* __restrict__ out, int ldout)
{
    __shared__ float tl[32][33];
    int r0 = blockIdx.y * 32, c0 = blockIdx.x * 32;
    int tx = threadIdx.x & 31, ty = threadIdx.x >> 5;
#pragma unroll
    for (int k = 0; k < 4; ++k)
        tl[ty + 8 * k][tx] = in[(size_t)(r0 + ty + 8 * k) * ldin + c0 + tx];
    __syncthreads();
#pragma unroll
    for (int k = 0; k < 4; ++k)
        out[(size_t)(c0 + ty + 8 * k) * ldout + r0 + tx] = f2bf(tl[tx][ty + 8 * k]);
}

__global__ __launch_bounds__(256) void transpose_bf16(
    const unsigned short* __restrict__ in, int ldin,
    unsigned short* __restrict__ out, int ldout)
{
    __shared__ unsigned short tl[32][33];
    int r0 = blockIdx.y * 32, c0 = blockIdx.x * 32;
    int tx = threadIdx.x & 31, ty = threadIdx.x >> 5;
#pragma unroll
    for (int k = 0; k < 4; ++k)
        tl[ty + 8 * k][tx] = in[(size_t)(r0 + ty + 8 * k) * ldin + c0 + tx];
    __syncthreads();
#pragma unroll
    for (int k = 0; k < 4; ++k)
        out[(size_t)(c0 + ty + 8 * k) * ldout + r0 + tx] = tl[tx][ty + 8 * k];
}

// ---------------------------------------------------------------------------
// Single-pass selective scan v7: ONE WAVE per (b,d); 8 waves/block sharing
// one batch's packed B/C via double-buffered LDS windows (R9 base, measured:
// 405us, VALUBusy 81%, FETCH 97MB, WRITE 66MB, occupancy capped at 4
// waves/SIMD by total work 4096 waves / 256 CU).
//   R10 change: the kernel is VALU-issue-bound -> pack the pairwise-
//   independent f32 math into <2 x float> ops so clang selects v_pk_*_f32
//   (gfx90a+ packed f32): exp-arg muls (16->8), dx*B muls (16->8),
//   h*C muls (16->8), fold adds (12->6). The serial h-fma chain and exp2
//   (trans pipe) stay scalar; permlane/shfl exchanges stay 32-bit.
//   Arithmetic is bit-identical, just packed. ~-30 VALU instrs/group.
// ---------------------------------------------------------------------------
#define SCHUNK 512
#define WSTEPS 32     // B/C window

#if __has_builtin(__builtin_amdgcn_permlane32_swap)
#define HAVE_PL32 1
#endif
#if __has_builtin(__builtin_amdgcn_permlane16_swap)
#define HAVE_PL16 1
#endif

// Packed fold stage 1 (xor32): pr2[i] (t=2i,2i+1) folded with pr2[i+4] (t+8).
// Per component: identical to R5-verified pl32_fold(x,y) = r.x + r.y.
#ifdef HAVE_PL32
#define FOLD_S1_PK                                                           \
    _Pragma("unroll")                                                        \
    for (int i = 0; i < 4; ++i) {                                            \
        f32x2_t xx = dir32 ? pr2[i + 4] : pr2[i];                            \
        f32x2_t yy = dir32 ? pr2[i] : pr2[i + 4];                            \
        u32x2_t ra = __builtin_amdgcn_permlane32_swap(                       \
            __float_as_uint(xx.x), __float_as_uint(yy.x), false, false);     \
        u32x2_t rb = __builtin_amdgcn_permlane32_swap(                       \
            __float_as_uint(xx.y), __float_as_uint(yy.y), false, false);     \
        f32x2_t va = {__uint_as_float(ra.x), __uint_as_float(rb.x)};         \
        f32x2_t vb = {__uint_as_float(ra.y), __uint_as_float(rb.y)};         \
        pr2[i] = va + vb;                                                    \
    }
#else
#define FOLD_S1_PK                                                           \
    _Pragma("unroll")                                                        \
    for (int i = 0; i < 4; ++i) {                                            \
        _Pragma("unroll")                                                    \
        for (int u = 0; u < 2; ++u) {                                        \
            float p0 = u ? pr2[i].y : pr2[i].x;                              \
            float p8 = u ? pr2[i + 4].y : pr2[i + 4].x;                      \
            float send = (lane & 32) ? p0 : p8;                              \
            float recv = __shfl_xor(send, 32);                               \
            float res = ((lane & 32) ? p8 : p0) + recv;                      \
            if (u) pr2[i].y = res; else pr2[i].x = res;                      \
        }                                                                    \
    }
#endif

// Packed fold stage 2 (xor16): pr2[i] folded with pr2[i+2], i<2.
#ifdef HAVE_PL16
#define FOLD_S2_PK                                                           \
    _Pragma("unroll")                                                        \
    for (int i = 0; i < 2; ++i) {                                            \
        f32x2_t xx = dir16 ? pr2[i + 2] : pr2[i];                            \
        f32x2_t yy = dir16 ? pr2[i] : pr2[i + 2];                            \
        u32x2_t ra = __builtin_amdgcn_permlane16_swap(                       \
            __float_as_uint(xx.x), __float_as_uint(yy.x), false, false);     \
        u32x2_t rb = __builtin_amdgcn_permlane16_swap(                       \
            __float_as_uint(xx.y), __float_as_uint(yy.y), false, false);     \
        f32x2_t va = {__uint_as_float(ra.x), __uint_as_float(rb.x)};         \
        f32x2_t vb = {__uint_as_float(ra.y), __uint_as_float(rb.y)};         \
        pr2[i] = va + vb;                                                    \
    }
#else
#define FOLD_S2_PK                                                           \
    _Pragma("unroll")                                                        \
    for (int i = 0; i < 2; ++i) {                                            \
        _Pragma("unroll")                                                    \
        for (int u = 0; u < 2; ++u) {                                        \
            float p0 = u ? pr2[i].y : pr2[i].x;                              \
            float p4 = u ? pr2[i + 2].y : pr2[i + 2].x;                      \
            float send = (lane & 16) ? p0 : p4;                              \
            float recv = __shfl_xor(send, 16);                               \
            float res = ((lane & 16) ? p4 : p0) + recv;                      \
            if (u) pr2[i].y = res; else pr2[i].x = res;                      \
        }                                                                    \
    }
#endif

// xor2 then xor1 butterfly on V: DPP quad_perm (stays within quads).
#if __has_builtin(__builtin_amdgcn_mov_dpp)
#define BFLY21(V)                                                            \
    V += __int_as_float(__builtin_amdgcn_mov_dpp(                            \
             __float_as_int(V), 0x4E, 0xF, 0xF, true));                      \
    V += __int_as_float(__builtin_amdgcn_mov_dpp(                            \
             __float_as_int(V), 0xB1, 0xF, 0xF, true));
#else
#define BFLY21(V)                                                            \
    V += __shfl_xor(V, 2);                                                   \
    V += __shfl_xor(V, 1);
#endif

// Cooperative async stage of window W's packed B/C (16KB linear) into
// s_bc2[DB]. Each wave copies 2x 1KB (64 lanes x 16B); global src per-lane,
// LDS dest wave-uniform base (+lane*16 by HW).
#define STAGE_BC(W, DB)                                                      \
{                                                                            \
    const float* wbase_ = bc2 + (size_t)(bQ + 8u * (unsigned)(W)) * 512;     \
    _Pragma("unroll")                                                        \
    for (int r_ = 0; r_ < 2; ++r_) {                                         \
        const float* src_ = wbase_ + (wid * 2 + r_) * 256 + lane * 4;        \
        __builtin_amdgcn_global_load_lds((const AS1 void*)src_,              \
            (AS3 void*)&s_bc2[DB][(wid * 2 + r_) * 256], 16, 0, 0);          \
    }                                                                        \
}

#define GROUP16(GG2, ZV)                                                     \
{                                                                            \
    const int gp = gpos + (GG2);        /* step base within chunk */         \
    const int t4b = (GG2) >> 2;                                              \
    f32x4_t bv4[4], cv4[4];                                                  \
    _Pragma("unroll")                                                        \
    for (int a = 0; a < 4; ++a) {       /* b128: 4 steps' B (or C) per read */\
        bv4[a] = *(const f32x4_t*)&sbcw[(t4b + a) * 512 + lane * 4];         \
        cv4[a] = *(const f32x4_t*)&sbcw[(t4b + a) * 512 + 256 + lane * 4];   \
    }                                                                        \
    f32x4_t d44[4], x44[4];                                                  \
    d44[0] = *(const f32x4_t*)&sdt[gp];                                      \
    d44[1] = *(const f32x4_t*)&sdt[gp + 4];                                  \
    d44[2] = *(const f32x4_t*)&sdt[gp + 8];                                  \
    d44[3] = *(const f32x4_t*)&sdt[gp + 12];                                 \
    x44[0] = *(const f32x4_t*)&sdtx[gp];                                     \
    x44[1] = *(const f32x4_t*)&sdtx[gp + 4];                                 \
    x44[2] = *(const f32x4_t*)&sdtx[gp + 8];                                 \
    x44[3] = *(const f32x4_t*)&sdtx[gp + 12];                                \
    f32x2_t e2[8], ib2[8], cvp[8];                                           \
    _Pragma("unroll")                                                        \
    for (int a = 0; a < 4; ++a) {       /* packed muls: v_pk_mul_f32 */      \
        e2[2*a]    = __builtin_shufflevector(d44[a], d44[a], 0, 1) * An2v;   \
        e2[2*a+1]  = __builtin_shufflevector(d44[a], d44[a], 2, 3) * An2v;   \
        ib2[2*a]   = __builtin_shufflevector(x44[a], x44[a], 0, 1)           \
                   * __builtin_shufflevector(bv4[a], bv4[a], 0, 1);          \
        ib2[2*a+1] = __builtin_shufflevector(x44[a], x44[a], 2, 3)           \
                   * __builtin_shufflevector(bv4[a], bv4[a], 2, 3);          \
        cvp[2*a]   = __builtin_shufflevector(cv4[a], cv4[a], 0, 1);          \
        cvp[2*a+1] = __builtin_shufflevector(cv4[a], cv4[a], 2, 3);          \
    }                                                                        \
    f32x2_t pr2[8];                                                          \
    _Pragma("unroll")                                                        \
    for (int i = 0; i < 8; ++i) {       /* serial h chain; packed h*C */     \
        float a0 = __builtin_amdgcn_exp2f(e2[i].x);                          \
        float a1 = __builtin_amdgcn_exp2f(e2[i].y);                          \
        f32x2_t hh;                                                          \
        h = fmaf(h, a0, ib2[i].x); hh.x = h;                                 \
        h = fmaf(h, a1, ib2[i].y); hh.y = h;                                 \
        pr2[i] = hh * cvp[i];                                                \
    }                                                                        \
    FOLD_S1_PK;                                                              \
    FOLD_S2_PK;                                                              \
    float prr[4] = {pr2[0].x, pr2[0].y, pr2[1].x, pr2[1].y};                 \
    _Pragma("unroll")                                                        \
    for (int t = 0; t < 2; ++t) {       /* fold xor8: 4 -> 2 */              \
        float send = (lane & 8) ? prr[t] : prr[t + 2];                       \
        float recv = __shfl_xor(send, 8);                                    \
        prr[t] = ((lane & 8) ? prr[t + 2] : prr[t]) + recv;                  \
    }                                                                        \
    {                                   /* fold xor4: 2 -> 1 */              \
        float send = (lane & 4) ? prr[0] : prr[1];                           \
        float recv = __shfl_xor(send, 4);                                    \
        prr[0] = ((lane & 4) ? prr[1] : prr[0]) + recv;                      \
    }                                                                        \
    BFLY21(prr[0]);                     /* butterfly over 4 n-residues */    \
    if ((lane & 3) == 0) {              /* 16 writer lanes, step (lane>>2)&15 */ \
        float xv = bf2f(sx[gp + myt16]);                                     \
        zrow[cbase + gp + myt16] = fmaf(Dd, xv, prr[0]) * (ZV);              \
    }                                                                        \
}

__global__ __launch_bounds__(512, 4) void scan_seq_kernel(
    const float* __restrict__ dtT,           // [2048][8192] fp32
    const unsigned short* __restrict__ xcT16,// [2048][8192] bf16
    const float* __restrict__ bc2,           // [2048][128][4] packed B/C
    float* __restrict__ zyT,                 // [2048][8192]: silu(z) in, y out
    const float* __restrict__ A_log,         // [2048][64]
    const float* __restrict__ Dp)            // [2048]
{
    __shared__ __align__(16) float s_dt[8][SCHUNK];           // 16 KB
    __shared__ __align__(16) float s_dtx[8][SCHUNK];          // 16 KB
    __shared__ __align__(16) unsigned short s_x[8][SCHUNK];   // 8 KB
    __shared__ __align__(16) float s_bc2[2][WSTEPS * 128];    // 32 KB (packed B/C)
    // 72 KB/block -> 2 blocks/CU, 16 waves/CU, 512 blocks = 1 round

    const int tid  = threadIdx.x;
    const int wid  = tid >> 6;              // 0..7
    const int lane = tid & 63;
    const int bi   = blockIdx.x;            // 0..511; bi&1 constant per XCD
    const int b    = bi & 1;                // all 8 waves share b -> shared B/C
    const int d    = (bi >> 1) * 8 + wid;
    const unsigned bQ = (unsigned)b * (L_SEQ / 4);   // t4 offset of this batch

    const size_t rowbase = (size_t)d * BL + (size_t)(b * L_SEQ);
    const float An2 = -__expf(A_log[d * D_STATE + lane]) * 1.44269504f;
    const f32x2_t An2v = {An2, An2};
    const float Dd  = Dp[d];

    // permlane swap-direction probes (uniform, once; HW-verified in R5)
#ifdef HAVE_PL32
    bool dir32;
    {
        u32x2_t r = __builtin_amdgcn_permlane32_swap((unsigned)lane,
                        (unsigned)lane + 1000u, false, false);
        dir32 = (__builtin_amdgcn_readfirstlane(r.x) == 1032u);
    }
#endif
#ifdef HAVE_PL16
    bool dir16;
    {
        u32x2_t r = __builtin_amdgcn_permlane16_swap((unsigned)lane,
                        (unsigned)lane + 1000u, false, false);
        dir16 = (__builtin_amdgcn_readfirstlane(r.x) == 1016u);
    }
#endif

    float* sdt = s_dt[wid];
    float* sdtx = s_dtx[wid];
    unsigned short* sx = s_x[wid];
    const float* dtrow = dtT + rowbase;
    const unsigned short* xrow = xcT16 + rowbase;
    float* zrow = zyT + rowbase;
    const int myt16 = (lane >> 2) & 15;     // step index this lane ends up with

    // prefetch chunk 0. dt loaded in the SAME element range as x (8 elems
    // per lane): pA = elems 8*lane..+3, pB = 8*lane+4..+7, pX = 8 bf16.
    float4 pA = ((const float4*)dtrow)[2 * lane];
    float4 pB = ((const float4*)dtrow)[2 * lane + 1];
    uint4  pX = ((const uint4*)xrow)[lane];

    float h = 0.f;
    int buf = 0;

    STAGE_BC(0, 0);                          // prologue: window 0 -> buf 0
    __syncthreads();

    for (int c = 0; c < L_SEQ / SCHUNK; ++c) {
        // stage current chunk's dt/x/dtx to this wave's private LDS slice.
        // dtx = dt*x computed ONCE here (amortized over 32 groups).
        ((float4*)sdt)[2 * lane]     = pA;
        ((float4*)sdt)[2 * lane + 1] = pB;
        ((uint4*)sx)[lane]           = pX;
        float4 dxA, dxB;
        dxA.x = pA.x * __uint_as_float(pX.x << 16);
        dxA.y = pA.y * __uint_as_float(pX.x & 0xffff0000u);
        dxA.z = pA.z * __uint_as_float(pX.y << 16);
        dxA.w = pA.w * __uint_as_float(pX.y & 0xffff0000u);
        dxB.x = pB.x * __uint_as_float(pX.z << 16);
        dxB.y = pB.y * __uint_as_float(pX.z & 0xffff0000u);
        dxB.z = pB.z * __uint_as_float(pX.w << 16);
        dxB.w = pB.w * __uint_as_float(pX.w & 0xffff0000u);
        ((float4*)sdtx)[2 * lane]     = dxA;
        ((float4*)sdtx)[2 * lane + 1] = dxB;

        if (c < L_SEQ / SCHUNK - 1) {       // register-prefetch next chunk
            pA = ((const float4*)(dtrow + (c + 1) * SCHUNK))[2 * lane];
            pB = ((const float4*)(dtrow + (c + 1) * SCHUNK))[2 * lane + 1];
            pX = ((const uint4*)(xrow + (c + 1) * SCHUNK))[lane];
        }
        const int cbase = c * SCHUNK;

        for (int wd = 0; wd < SCHUNK / WSTEPS; ++wd) {
            const int wglob = c * (SCHUNK / WSTEPS) + wd;
            if (wglob + 1 < L_SEQ / WSTEPS)  // issue next window's staging EARLY
                STAGE_BC(wglob + 1, buf ^ 1);
            const int gpos = wd * WSTEPS;
            // hoist z for both groups: full-group latency cover
            float zv0 = 0.f, zv1 = 0.f;
            if ((lane & 3) == 0) {
                zv0 = zrow[cbase + gpos + myt16];
                zv1 = zrow[cbase + gpos + 16 + myt16];
            }
            const float* sbcw = s_bc2[buf];
            GROUP16(0, zv0);
            GROUP16(16, zv1);
            __syncthreads();                 // staging had a full window to land
            buf ^= 1;
        }
    }
}

// ---------------------------------------------------------------------------
extern "C" void kernel_launch(void* const* d_in, const int* in_sizes, int n_in,
                              void* d_out, int out_size, void* d_ws, size_t ws_size,
                              hipStream_t stream)
{
    const float* hs        = (const float*)d_in[0];  // [8192][1024]
    const float* in_proj_w = (const float*)d_in[1];  // [4096][1024]
    const float* conv_w    = (const float*)d_in[2];  // [2048][4]
    const float* conv_b    = (const float*)d_in[3];  // [2048]
    const float* x_proj_w  = (const float*)d_in[4];  // [256][2048]
    const float* dt_proj_w = (const float*)d_in[5];  // [2048][128]
    const float* dt_proj_b = (const float*)d_in[6];  // [2048]
    const float* A_log     = (const float*)d_in[7];  // [2048][64]
    const float* Dp        = (const float*)d_in[8];  // [2048]
    const float* out_proj_w= (const float*)d_in[9];  // [1024][2048]
    float* out = (float*)d_out;                      // [8192][1024]

    // workspace map (MiB offsets; peak ~177.5 MiB):
    //  S0 @0   : xT fp32 (64) -> xc16 bf16 (32) @0 -> dtT fp32 (64) @0
    //  S1 @64  : zT fp32 (64)  (scan writes y in place)
    //  S2 @128 : W1_16 (8)@128 + hs16 (16)@136 -> xcT16 bf16 (32)@128 -> y16 (32)@128
    //  tail    : xdbl fp32 (8)@160, xdbl16 (2)@169 -> bc2 (4)@169 (xdbl16,
    //            Wx16, Wdt16 all dead by repack time), Wx16 (1)@171,
    //            Wdt16 (.5)@172, Wo16 (4)@173  (end 177)
    char* ws = (char*)d_ws;
    const size_t MiB = 1024 * 1024;
    float*          xT    = (float*)(ws);
    unsigned short* xc16  = (unsigned short*)(ws);
    float*          dtT   = (float*)(ws);
    float*          zT    = (float*)(ws + 64 * MiB);
    unsigned short* W1_16 = (unsigned short*)(ws + 128 * MiB);
    unsigned short* hs16  = (unsigned short*)(ws + 136 * MiB);
    unsigned short* xcT16 = (unsigned short*)(ws + 128 * MiB);
    unsigned short* y16   = (unsigned short*)(ws + 128 * MiB);
    float*          xdbl  = (float*)(ws + 160 * MiB);
    unsigned short* xdbl16= (unsigned short*)(ws + 169 * MiB);
    float*          bc2   = (float*)(ws + 169 * MiB);   // reuses dead region
    unsigned short* Wx16  = (unsigned short*)(ws + 171 * MiB);
    unsigned short* Wdt16 = (unsigned short*)(ws + 172 * MiB);
    unsigned short* Wo16  = (unsigned short*)(ws + 173 * MiB);

    dim3 blk(256);

    // bf16 conversions
    cvt_f32_bf16<<<8192, blk, 0, stream>>>(hs, hs16, 2097152);
    cvt_f32_bf16<<<4096, blk, 0, stream>>>(in_proj_w, W1_16, 1048576);
    cvt_f32_bf16<<<512, blk, 0, stream>>>(x_proj_w, Wx16, 131072);
    cvt_f32_bf16<<<256, blk, 0, stream>>>(dt_proj_w, Wdt16, 65536);
    cvt_f32_bf16<<<2048, blk, 0, stream>>>(out_proj_w, Wo16, 524288);

    // 1) xT[d][m] = W1x . hs^T   (M=2048, N=8192, K=1024)
    gemm_bf16<<<dim3(64, 16), blk, 0, stream>>>(
        W1_16, D_MODEL, hs16, D_MODEL, xT, BL, D_MODEL, nullptr, 0);

    // 2) zT[d][m] = silu(W1z . hs^T)
    gemm_bf16<<<dim3(64, 16), blk, 0, stream>>>(
        W1_16 + (size_t)D_INNER * D_MODEL, D_MODEL, hs16, D_MODEL,
        zT, BL, D_MODEL, nullptr, 2);

    // 3) xcT16 = bf16(silu(conv(xT) + b))
    conv_silu_kernel<<<(D_INNER * (BL / 4)) / 256, blk, 0, stream>>>(
        xT, conv_w, conv_b, xcT16);

    // 4) xc16[m][d] = transpose(xcT16)
    transpose_bf16<<<dim3(BL / 32, D_INNER / 32), blk, 0, stream>>>(
        xcT16, BL, xc16, D_INNER);

    // 5) xdbl[m][256] = xc . x_proj^T   (M=8192, N=256, K=2048)
    gemm_bf16<<<dim3(2, 64), blk, 0, stream>>>(
        xc16, D_INNER, Wx16, D_INNER, xdbl, 256, D_INNER, nullptr, 0);

    // 6) xdbl16 = bf16(xdbl[:, :128])
    cvt_dtpart<<<1024, blk, 0, stream>>>(xdbl, xdbl16);

    // 7) dtT[d][m] = softplus(Wdt . xdbl_dt^T + b[d])  (M=2048, N=8192, K=128)
    gemm_bf16<<<dim3(64, 16), blk, 0, stream>>>(
        Wdt16, DT_RANK, xdbl16, DT_RANK, dtT, BL, DT_RANK, dt_proj_b, 1);

    // 7b) pack B/C for b128 LDS reads in the scan
    repack_bc<<<1024, blk, 0, stream>>>(xdbl, bc2);

    // 8) single-pass scan: 1 wave per (b,d), 8 waves/block, packed B/C LDS
    scan_seq_kernel<<<512, dim3(512), 0, stream>>>(
        dtT, xcT16, bc2, zT, A_log, Dp);

    // 9) y16[m][d] = bf16(transpose(zT))
    transpose_f32_bf16<<<dim3(BL / 32, D_INNER / 32), blk, 0, stream>>>(
        zT, BL, y16, D_INNER);

    // 10) out = y . out_proj^T   (M=8192, N=1024, K=2048)
    gemm_bf16<<<dim3(8, 64), blk, 0, stream>>>(
        y16, D_INNER, Wo16, D_INNER, out, D_MODEL, D_INNER, nullptr, 0);
}